// Round 1
// baseline (16301.270 us; speedup 1.0000x reference)
//
#include <hip/hip_runtime.h>

// ---------------------------------------------------------------------------
// TTS forward on MI355X.
//   embed -> conv1(+BN+ReLU) -> conv2(+BN+ReLU) -> persistent biLSTM encoder
//   -> W_eff fold (decoder input GEMM folded into recurrent weights)
//   -> persistent 800-step decoder LSTM (fused mel/gate output duty)
// Round 4: tree barrier removed. h-state exchange is now dataflow-synced:
// per-producer-wave flags (value = step) written after the wave's own
// vmcnt(0) ack of its sc0/sc1 write-through h stores; consumers spin on the
// slot's flag array, then load the never-reused ring addresses as before.
// Cuts ~6 serialized L3 round trips per step to ~3.5-4.
// ---------------------------------------------------------------------------

typedef float f4 __attribute__((ext_vector_type(4)));
typedef _Float16 h8 __attribute__((ext_vector_type(8)));
typedef _Float16 half_t;
typedef unsigned long long u64;

#define B_    32
#define LTXT  256
#define TMEL  800
#define EE    512
#define HH    512
#define DD    1024
#define MM    128
#define NROWS 8192          // B_*LTXT
#define GATE_OFF 3276800    // B_*TMEL*MM
#define MASK_OFF 3302400    // + B_*TMEL

#define RING_D 801          // decoder h ring slots (never reused in 800 steps)
#define RING_E 257          // encoder h ring slots
#define HOP    13           // slot hop stride (coprime with both rings)

// workspace offsets (bytes)
#define WS_FLAGE      0ull             // RING_E*128 u32 (131584 B, reserve 256K)
#define WS_FLAGD      262144ull        // RING_D*128 u32 (410112 B, reserve 512K)
#define WS_HENC       786432ull        // RING_E * 65536
#define WS_ZERO_BYTES 851968ull        // flags + henc slot 0
#define WS_HD         17629184ull      // RING_D * 65536
#define WS_BUFX       70123520ull      // 8 MiB
#define WS_BUFY       78512128ull      // 8 MiB
#define WS_CONVF      86900736ull      // 16 MiB (reused by WEFF/W0 after convs)
#define WS_WEFF       86900736ull
#define WS_W0         95289344ull
#define WS_WP1        103677952ull
#define WS_WP2        105250816ull
#define WS_WIHP       106823680ull     // 4 MiB
#define WS_WHHP       111017984ull     // 4 MiB
#define WS_BSUM       115212288ull
#define WS_BEFF       115228672ull
#define WS_B0         115245056ull
#define WS_MEAN       115261440ull
#define WS_RSTD       115263488ull
#define WS_PROJW      115265536ull
#define WS_PROJG      115527680ull
#define WS_CEL        115560448ull
// total ~115.7 MB

__device__ __forceinline__ float sigm(float x) { return 1.f / (1.f + __expf(-x)); }
__device__ __forceinline__ float tanh_f(float x) {
    float e = __expf(2.f * x);
    return 1.f - 2.f / (e + 1.f);
}

// write-through store (bypass L1/L2, land at L3 coherence point), non-atomic
__device__ __forceinline__ void st_wt64(void* p, u64 v) {
    asm volatile("global_store_dwordx2 %0, %1, off sc0 sc1" :: "v"(p), "v"(v) : "memory");
}

// ---------------- small prep kernels ----------------

__global__ void k_embed(const int* __restrict__ x, const float* __restrict__ emb,
                        half_t* __restrict__ out) {
    int row = blockIdx.x;
    int tok = x[row];
    const float* e = emb + (size_t)tok * EE;
    half_t* o = out + (size_t)row * EE;
    for (int c = threadIdx.x; c < EE; c += blockDim.x) o[c] = (half_t)e[c];
}

__global__ void k_packconvw(const float* __restrict__ w, half_t* __restrict__ wp) {
    int idx = blockIdx.x * 256 + threadIdx.x;
    if (idx >= 3 * EE * EE) return;
    int s = idx / (EE * EE);
    int rem = idx - s * EE * EE;
    int eo = rem >> 9, ei = rem & 511;
    wp[idx] = (half_t)w[(size_t)eo * (EE * 3) + ei * 3 + s];
}

__global__ __launch_bounds__(256) void k_conv(const half_t* __restrict__ A,
                                              const half_t* __restrict__ Wp,
                                              const float* __restrict__ bias,
                                              float* __restrict__ out) {
    const int nt = blockIdx.x, et = blockIdx.y;
    const int tid = threadIdx.x;
    const int wv = tid >> 6, l = tid & 63, quad = l >> 4, lo = l & 15;
    const int rowA = nt * 64 + wv * 16 + lo;
    const int eo = et * 16 + lo;
    f4 acc = {0.f, 0.f, 0.f, 0.f};
    for (int s = 0; s < 3; ++s) {
        int lsp = (rowA & 255) + s - 1;
        bool valid = (lsp >= 0) && (lsp < 256);
        int rs = rowA + s - 1;
        rs = rs < 0 ? 0 : (rs > NROWS - 1 ? NROWS - 1 : rs);
        const half_t* ab = A + (size_t)rs * EE;
        const half_t* wb = Wp + ((size_t)s * EE + eo) * EE;
#pragma unroll 4
        for (int ks = 0; ks < 16; ++ks) {
            h8 a = {0, 0, 0, 0, 0, 0, 0, 0};
            if (valid) a = *(const h8*)(ab + ks * 32 + quad * 8);
            h8 b = *(const h8*)(wb + ks * 32 + quad * 8);
            acc = __builtin_amdgcn_mfma_f32_16x16x32_f16(a, b, acc, 0, 0, 0);
        }
    }
    const int orow = nt * 64 + wv * 16 + quad * 4;
    const float bv = bias[eo];
#pragma unroll
    for (int r = 0; r < 4; ++r) out[(size_t)(orow + r) * EE + eo] = acc[r] + bv;
}

__global__ __launch_bounds__(256) void k_bnstats(const float* __restrict__ x,
                                                 float* __restrict__ mean,
                                                 float* __restrict__ rstd) {
    const int c = blockIdx.x;
    float s = 0.f, ss = 0.f;
    for (int n = threadIdx.x; n < NROWS; n += 256) {
        float v = x[(size_t)n * EE + c];
        s += v; ss += v * v;
    }
#pragma unroll
    for (int off = 32; off > 0; off >>= 1) { s += __shfl_down(s, off); ss += __shfl_down(ss, off); }
    __shared__ float as[4], ass[4];
    int wv = threadIdx.x >> 6;
    if ((threadIdx.x & 63) == 0) { as[wv] = s; ass[wv] = ss; }
    __syncthreads();
    if (threadIdx.x == 0) {
        float S = as[0] + as[1] + as[2] + as[3];
        float SS = ass[0] + ass[1] + ass[2] + ass[3];
        float m = S / (float)NROWS;
        float var = SS / (float)NROWS - m * m;
        mean[c] = m;
        rstd[c] = rsqrtf(var + 1e-5f);
    }
}

__global__ void k_bnapply(const float* __restrict__ x, const float* __restrict__ mean,
                          const float* __restrict__ rstd, const float* __restrict__ g,
                          const float* __restrict__ beta, half_t* __restrict__ out) {
    int idx = blockIdx.x * 256 + threadIdx.x;
    if (idx >= NROWS * EE) return;
    int c = idx & (EE - 1);
    float v = (x[idx] - mean[c]) * rstd[c] * g[c] + beta[c];
    out[idx] = (half_t)(v > 0.f ? v : 0.f);
}

__global__ void k_packrec(const float* __restrict__ src, half_t* __restrict__ dst,
                          int Hdim, int kshift, int total) {
    int idx = blockIdx.x * 256 + threadIdx.x;
    if (idx >= total) return;
    int p = idx >> kshift;
    int k = idx & ((1 << kshift) - 1);
    int he = p >> 2, g = p & 3;
    dst[idx] = (half_t)src[((size_t)g * Hdim + he) * (size_t)(1 << kshift) + k];
}

__global__ void k_bsumenc(const float* __restrict__ bf, const float* __restrict__ bhf,
                          const float* __restrict__ bb, const float* __restrict__ bhb,
                          float* __restrict__ bsum) {
    int p = blockIdx.x * 256 + threadIdx.x;
    if (p >= 4096) return;
    int dir = p >> 11, pp = p & 2047;
    int he = pp >> 2, g = pp & 3;
    int row = g * HH + he;
    bsum[p] = dir ? (bb[row] + bhb[row]) : (bf[row] + bhf[row]);
}

__global__ __launch_bounds__(256) void k_weff(const float* __restrict__ dwhh,
                                              const float* __restrict__ dwih,
                                              const float* __restrict__ projw,
                                              half_t* __restrict__ weff,
                                              half_t* __restrict__ w0) {
    int row = blockIdx.x;
    int k = blockIdx.y * 256 + threadIdx.x;
    float v = dwhh[(size_t)row * DD + k];
    float acc = v;
    for (int m = 0; m < MM; ++m) acc += dwih[(size_t)row * MM + m] * projw[(size_t)m * DD + k];
    int p = ((row & (DD - 1)) << 2) | (row >> 10);
    weff[(size_t)p * DD + k] = (half_t)acc;
    w0[(size_t)p * DD + k] = (half_t)v;
}

__global__ void k_bdec(const float* __restrict__ dbih, const float* __restrict__ dbhh,
                       const float* __restrict__ dwih, const float* __restrict__ projb,
                       float* __restrict__ beff, float* __restrict__ b0) {
    int p = blockIdx.x * 256 + threadIdx.x;
    if (p >= 4096) return;
    int he = p >> 2, g = p & 3;
    int row = g * DD + he;
    float bb = dbih[row] + dbhh[row];
    float acc = bb;
    for (int m = 0; m < MM; ++m) acc += dwih[(size_t)row * MM + m] * projb[m];
    b0[p] = bb;
    beff[p] = acc;
}

__global__ void k_cast(const float* __restrict__ src, half_t* __restrict__ dst, int n) {
    int idx = blockIdx.x * 256 + threadIdx.x;
    if (idx < n) dst[idx] = (half_t)src[idx];
}

__global__ void k_projg(const float* __restrict__ gw, half_t* __restrict__ pg) {
    int idx = blockIdx.x * 256 + threadIdx.x;
    if (idx >= 16 * DD) return;
    int row = idx >> 10, k = idx & (DD - 1);
    pg[idx] = (half_t)(row == 0 ? gw[k] : 0.f);
}

__global__ void k_mask(const int* __restrict__ lens, float* __restrict__ out) {
    int idx = blockIdx.x * 256 + threadIdx.x;
    if (idx >= B_ * TMEL) return;
    int b = idx / TMEL, t = idx - b * TMEL;
    out[MASK_OFF + idx] = (t > lens[b]) ? 1.f : 0.f;
}

// ---------------- persistent bidirectional encoder LSTM ----------------
// 64 blocks x 512 thr. dir=j>>5 (independent flag ranges), sub=j&31 owns
// 16 h-elems. h ring: slot sp read, slot sn written (never-reused addresses).
// Sync: per-producer-wave flag (value = t+1) stored after the wave's own
// vmcnt(0); consumers spin on the 64 flags of their dir, then load.
__global__ __launch_bounds__(512) void k_enc(const half_t* __restrict__ X,
                                             const half_t* __restrict__ wihp,
                                             const half_t* __restrict__ whhp,
                                             const float* __restrict__ bsum,
                                             const int* __restrict__ lens,
                                             half_t* __restrict__ henc,   // ring [RING_E][2][32][512]
                                             half_t* __restrict__ hd0,    // ring slot 0: [32][1024]
                                             float* __restrict__ cel,     // [32][1024]
                                             unsigned* __restrict__ flagE) { // [RING_E][128]
    const int j = blockIdx.x;
    const int dir = j >> 5, sub = j & 31;
    const int tid = threadIdx.x;
    const int wv = tid >> 6, l = tid & 63, quad = l >> 4, lo = l & 15;
    const int rg = wv >> 1, bh = wv & 1;
    const int bfr = bh * 16 + lo;
    const int ue = tid >> 5, ub = tid & 31;

    __shared__ half_t s_hd[32 * 520];
    __shared__ float s_g[32][65];
    __shared__ float s_c[16][32];
    __shared__ float s_h[16][32];
    __shared__ half_t s_hh[16][32];
    __shared__ int s_len[32];

    if (tid < 32) s_len[tid] = lens[tid];
    s_c[ue][ub] = 0.f;
    s_h[ue][ub] = 0.f;

    const int pr = dir * 2048 + sub * 64 + rg * 16 + lo;
    const half_t* wih_b = wihp + (size_t)pr * 512;
    const half_t* whh_b = whhp + (size_t)pr * 512;
    const float bias_n = bsum[pr];

    int sp = 0, sn = HOP;
    __syncthreads();

    for (int t = 0; t < 256; ++t) {
        // wait for all producers of slot sp (slot 0 pre-zeroed => skip)
        if (t > 0) {
            if (tid < 64) {
                const unsigned want = (unsigned)t;
                const unsigned* fp = flagE + (size_t)sp * 128 + dir * 64 + tid;
                while (__hip_atomic_load(fp, __ATOMIC_RELAXED, __HIP_MEMORY_SCOPE_AGENT) < want)
                    __builtin_amdgcn_s_sleep(1);
            }
            __syncthreads();
        }

        // issue h-slot coop loads (fresh cold addresses -> L3)
        const half_t* src = henc + (size_t)sp * 32768 + (size_t)dir * 16384;
        h8 tmp0 = *(const h8*)(src + (size_t)(tid + 0 * 512) * 8);
        h8 tmp1 = *(const h8*)(src + (size_t)(tid + 1 * 512) * 8);
        h8 tmp2 = *(const h8*)(src + (size_t)(tid + 2 * 512) * 8);
        h8 tmp3 = *(const h8*)(src + (size_t)(tid + 3 * 512) * 8);

        // x-part MFMA overlaps the h loads
        const int lb = s_len[bfr];
        int tt = (dir == 0) ? t : (lb - 1 - t);
        tt = tt < 0 ? 0 : tt;
        const half_t* xr = X + ((size_t)bfr * 256 + tt) * 512;
        f4 accA = {0.f, 0.f, 0.f, 0.f}, accB = {0.f, 0.f, 0.f, 0.f};
#pragma unroll 4
        for (int ks = 0; ks < 16; ++ks) {
            h8 a = *(const h8*)(xr + ks * 32 + quad * 8);
            h8 b = *(const h8*)(wih_b + ks * 32 + quad * 8);
            accA = __builtin_amdgcn_mfma_f32_16x16x32_f16(a, b, accA, 0, 0, 0);
        }

        // stage h into LDS
        {
            int c0 = tid;
            *(h8*)(s_hd + (size_t)(c0 >> 6) * 520 + (c0 & 63) * 8) = tmp0;
            int c1 = tid + 512;
            *(h8*)(s_hd + (size_t)(c1 >> 6) * 520 + (c1 & 63) * 8) = tmp1;
            int c2 = tid + 1024;
            *(h8*)(s_hd + (size_t)(c2 >> 6) * 520 + (c2 & 63) * 8) = tmp2;
            int c3 = tid + 1536;
            *(h8*)(s_hd + (size_t)(c3 >> 6) * 520 + (c3 & 63) * 8) = tmp3;
        }
        __syncthreads();

#pragma unroll 4
        for (int ks = 0; ks < 16; ++ks) {
            h8 a = *(const h8*)(s_hd + (size_t)bfr * 520 + ks * 32 + quad * 8);
            h8 b = *(const h8*)(whh_b + ks * 32 + quad * 8);
            accB = __builtin_amdgcn_mfma_f32_16x16x32_f16(a, b, accB, 0, 0, 0);
        }
        const int bm = bh * 16 + quad * 4, cm = rg * 16 + lo;
#pragma unroll
        for (int r = 0; r < 4; ++r) s_g[bm + r][cm] = accA[r] + accB[r] + bias_n;
        __syncthreads();
        {
            float gi = s_g[ub][ue * 4 + 0], gf = s_g[ub][ue * 4 + 1];
            float gg = s_g[ub][ue * 4 + 2], go = s_g[ub][ue * 4 + 3];
            float cn = sigm(gf) * s_c[ue][ub] + sigm(gi) * tanh_f(gg);
            float hn = sigm(go) * tanh_f(cn);
            if (t < s_len[ub]) { s_c[ue][ub] = cn; s_h[ue][ub] = hn; }
            s_hh[ue][ub] = (half_t)s_h[ue][ub];
        }
        __syncthreads();
        if (tid < 128 && t < 255) {
            int eq = tid >> 5, b2 = tid & 31;
            union { half_t h[4]; u64 u; } pk;
            pk.h[0] = s_hh[eq * 4 + 0][b2]; pk.h[1] = s_hh[eq * 4 + 1][b2];
            pk.h[2] = s_hh[eq * 4 + 2][b2]; pk.h[3] = s_hh[eq * 4 + 3][b2];
            st_wt64(henc + (size_t)sn * 32768 + (size_t)dir * 16384
                    + (size_t)b2 * 512 + sub * 16 + eq * 4, pk.u);
            // per-wave ack of own data stores, then publish this wave's flag
            asm volatile("s_waitcnt vmcnt(0)");
            if ((tid & 63) == 0)
                __hip_atomic_store(flagE + (size_t)sn * 128 + dir * 64 + sub * 2 + (tid >> 6),
                                   (unsigned)(t + 1), __ATOMIC_RELAXED,
                                   __HIP_MEMORY_SCOPE_AGENT);
        }
        if (t < 255) { sp = sn; sn += HOP; if (sn >= RING_E) sn -= RING_E; }
    }
    hd0[(size_t)ub * 1024 + dir * 512 + sub * 16 + ue] = (half_t)s_h[ue][ub];
    cel[(size_t)ub * 1024 + dir * 512 + sub * 16 + ue] = s_c[ue][ub];
}

// ---------------- persistent decoder LSTM ----------------
// 64 blocks x 512 thr, block j owns h-elems [16j,16j+16). h ring slots hop by
// HOP mod RING_D; slot 0 = encoder final hid. Flag sync as in k_enc:
// 2 flags per producer block (one per storing wave), value = t.
__global__ __launch_bounds__(512) void k_dec(const half_t* __restrict__ Weff,
                                             const half_t* __restrict__ W0,
                                             const float* __restrict__ beff,
                                             const float* __restrict__ b0,
                                             const half_t* __restrict__ projwb,
                                             const half_t* __restrict__ projg,
                                             const float* __restrict__ projb,
                                             const float* __restrict__ gateb,
                                             const int* __restrict__ mlens,
                                             const float* __restrict__ cel,
                                             half_t* __restrict__ hd,   // ring [RING_D][32][1024]
                                             float* __restrict__ out,
                                             unsigned* __restrict__ flagD) { // [RING_D][128]
    const int j = blockIdx.x;
    const int tid = threadIdx.x;
    const int wv = tid >> 6, l = tid & 63, quad = l >> 4, lo = l & 15;
    const int rg = wv >> 1, bh = wv & 1;
    const int bfr = bh * 16 + lo;
    const int ue = tid >> 5, ub = tid & 31;

    __shared__ half_t s_hd[32 * 1032];
    __shared__ float s_g[32][65];
    __shared__ float s_c[16][32];
    __shared__ half_t s_hh[16][32];
    __shared__ int s_len[32];

    if (tid < 32) s_len[tid] = mlens[tid];
    s_c[ue][ub] = cel[(size_t)ub * 1024 + j * 16 + ue];
    const int pr = j * 64 + rg * 16 + lo;
    const float biasE = beff[pr], bias0 = b0[pr];
    const bool meld = (j < 8), gated = (j == 8);
    const bool duty = (meld || gated) && (rg == 0);
    const half_t* pw = nullptr;
    float biasP = 0.f;
    if (duty) {
        pw = meld ? (projwb + (size_t)(j * 16 + lo) * 1024) : (projg + (size_t)lo * 1024);
        biasP = meld ? projb[j * 16 + lo] : gateb[0];
    }
    const half_t* wbE = Weff + (size_t)pr * 1024;
    const half_t* wb0 = W0 + (size_t)pr * 1024;

    int sp = 0, sn = HOP;
    __syncthreads();

    for (int t = 1; t <= TMEL; ++t) {
        // wait for all producers of slot sp (t==1: slot 0 from k_enc, visible
        // via kernel-boundary coherence => skip)
        if (t > 1) {
            if (tid < 128) {
                const unsigned want = (unsigned)(t - 1);
                const unsigned* fp = flagD + (size_t)sp * 128 + tid;
                while (__hip_atomic_load(fp, __ATOMIC_RELAXED, __HIP_MEMORY_SCOPE_AGENT) < want)
                    __builtin_amdgcn_s_sleep(1);
            }
            __syncthreads();
        }

        // cooperative load of h slot (fresh cold addresses)
        const half_t* src = hd + (size_t)sp * 32768;
        {
            h8 tp[8];
#pragma unroll
            for (int i = 0; i < 8; ++i)
                tp[i] = *(const h8*)(src + (size_t)(tid + i * 512) * 8);
#pragma unroll
            for (int i = 0; i < 8; ++i) {
                int c = tid + i * 512;
                *(h8*)(s_hd + (size_t)(c >> 7) * 1032 + (c & 127) * 8) = tp[i];
            }
        }
        __syncthreads();

        const half_t* wb = (t == 1) ? wb0 : wbE;
        const half_t* ar = s_hd + (size_t)bfr * 1032 + quad * 8;
        f4 acc = {0.f, 0.f, 0.f, 0.f}, acc2 = {0.f, 0.f, 0.f, 0.f};
        if (duty && t >= 2) {
            f4 accm = {0.f, 0.f, 0.f, 0.f}, accm2 = {0.f, 0.f, 0.f, 0.f};
#pragma unroll 8
            for (int ks = 0; ks < 32; ks += 2) {
                h8 a0 = *(const h8*)(ar + ks * 32);
                h8 a1 = *(const h8*)(ar + ks * 32 + 32);
                acc = __builtin_amdgcn_mfma_f32_16x16x32_f16(a0, *(const h8*)(wb + ks * 32 + quad * 8), acc, 0, 0, 0);
                acc2 = __builtin_amdgcn_mfma_f32_16x16x32_f16(a1, *(const h8*)(wb + ks * 32 + 32 + quad * 8), acc2, 0, 0, 0);
                accm = __builtin_amdgcn_mfma_f32_16x16x32_f16(a0, *(const h8*)(pw + ks * 32 + quad * 8), accm, 0, 0, 0);
                accm2 = __builtin_amdgcn_mfma_f32_16x16x32_f16(a1, *(const h8*)(pw + ks * 32 + 32 + quad * 8), accm2, 0, 0, 0);
            }
            accm[0] += accm2[0]; accm[1] += accm2[1]; accm[2] += accm2[2]; accm[3] += accm2[3];
            const int pos = t - 2;
            if (meld) {
#pragma unroll
                for (int r = 0; r < 4; ++r) {
                    int b = bh * 16 + quad * 4 + r;
                    float v = accm[r] + biasP;
                    if (pos > s_len[b]) v = 0.f;
                    __builtin_nontemporal_store(v,
                        &out[(size_t)b * (TMEL * MM) + (size_t)pos * MM + j * 16 + lo]);
                }
            } else if (lo == 0) {
#pragma unroll
                for (int r = 0; r < 4; ++r) {
                    int b = bh * 16 + quad * 4 + r;
                    float v = accm[r] + biasP;
                    if (pos > s_len[b]) v = 1000.f;
                    __builtin_nontemporal_store(v, &out[GATE_OFF + (size_t)b * TMEL + pos]);
                }
            }
        } else {
#pragma unroll 8
            for (int ks = 0; ks < 32; ks += 2) {
                h8 a0 = *(const h8*)(ar + ks * 32);
                h8 a1 = *(const h8*)(ar + ks * 32 + 32);
                acc = __builtin_amdgcn_mfma_f32_16x16x32_f16(a0, *(const h8*)(wb + ks * 32 + quad * 8), acc, 0, 0, 0);
                acc2 = __builtin_amdgcn_mfma_f32_16x16x32_f16(a1, *(const h8*)(wb + ks * 32 + 32 + quad * 8), acc2, 0, 0, 0);
            }
        }
        const float bn = (t == 1) ? bias0 : biasE;
        const int bm = bh * 16 + quad * 4, cm = rg * 16 + lo;
#pragma unroll
        for (int r = 0; r < 4; ++r) s_g[bm + r][cm] = acc[r] + acc2[r] + bn;
        __syncthreads();
        {
            float gi = s_g[ub][ue * 4 + 0], gf = s_g[ub][ue * 4 + 1];
            float gg = s_g[ub][ue * 4 + 2], go = s_g[ub][ue * 4 + 3];
            float cn = sigm(gf) * s_c[ue][ub] + sigm(gi) * tanh_f(gg);
            s_c[ue][ub] = cn;
            s_hh[ue][ub] = (half_t)(sigm(go) * tanh_f(cn));
        }
        __syncthreads();
        if (tid < 128) {
            int eq = tid >> 5, b2 = tid & 31;
            union { half_t h[4]; u64 u; } pk;
            pk.h[0] = s_hh[eq * 4 + 0][b2]; pk.h[1] = s_hh[eq * 4 + 1][b2];
            pk.h[2] = s_hh[eq * 4 + 2][b2]; pk.h[3] = s_hh[eq * 4 + 3][b2];
            st_wt64(hd + (size_t)sn * 32768 + (size_t)b2 * 1024 + j * 16 + eq * 4, pk.u);
            // per-wave ack of own data stores, then publish this wave's flag
            asm volatile("s_waitcnt vmcnt(0)");
            if ((tid & 63) == 0)
                __hip_atomic_store(flagD + (size_t)sn * 128 + j * 2 + (tid >> 6),
                                   (unsigned)t, __ATOMIC_RELAXED,
                                   __HIP_MEMORY_SCOPE_AGENT);
        }
        sp = sn; sn += HOP; if (sn >= RING_D) sn -= RING_D;
    }
    // epilogue: outputs for pos 799 from h_800 (slot sp)
    if (meld || gated) {
        if (tid < 128) {
            const unsigned* fp = flagD + (size_t)sp * 128 + tid;
            while (__hip_atomic_load(fp, __ATOMIC_RELAXED, __HIP_MEMORY_SCOPE_AGENT) < (unsigned)TMEL)
                __builtin_amdgcn_s_sleep(1);
        }
        __syncthreads();
        const half_t* src = hd + (size_t)sp * 32768;
        {
            h8 tp[8];
#pragma unroll
            for (int i = 0; i < 8; ++i)
                tp[i] = *(const h8*)(src + (size_t)(tid + i * 512) * 8);
#pragma unroll
            for (int i = 0; i < 8; ++i) {
                int c = tid + i * 512;
                *(h8*)(s_hd + (size_t)(c >> 7) * 1032 + (c & 127) * 8) = tp[i];
            }
        }
        __syncthreads();
        if (duty) {
            const half_t* ar = s_hd + (size_t)bfr * 1032 + quad * 8;
            f4 accm = {0.f, 0.f, 0.f, 0.f};
#pragma unroll 4
            for (int ks = 0; ks < 32; ++ks) {
                h8 a = *(const h8*)(ar + ks * 32);
                accm = __builtin_amdgcn_mfma_f32_16x16x32_f16(a, *(const h8*)(pw + ks * 32 + quad * 8), accm, 0, 0, 0);
            }
            if (meld) {
#pragma unroll
                for (int r = 0; r < 4; ++r) {
                    int b = bh * 16 + quad * 4 + r;
                    float v = accm[r] + biasP;
                    if (799 > s_len[b]) v = 0.f;
                    out[(size_t)b * (TMEL * MM) + (size_t)799 * MM + j * 16 + lo] = v;
                }
            } else if (lo == 0) {
#pragma unroll
                for (int r = 0; r < 4; ++r) {
                    int b = bh * 16 + quad * 4 + r;
                    float v = accm[r] + biasP;
                    if (799 > s_len[b]) v = 1000.f;
                    out[GATE_OFF + (size_t)b * TMEL + 799] = v;
                }
            }
        }
    }
}

// ---------------------------------------------------------------------------

extern "C" void kernel_launch(void* const* d_in, const int* in_sizes, int n_in,
                              void* d_out, int out_size, void* d_ws, size_t ws_size,
                              hipStream_t stream) {
    const int* x = (const int*)d_in[0];
    const int* tlens = (const int*)d_in[1];
    const int* mlens = (const int*)d_in[3];
    const float* emb = (const float*)d_in[4];
    const float* c1w = (const float*)d_in[5];
    const float* c1b = (const float*)d_in[6];
    const float* bn1g = (const float*)d_in[7];
    const float* bn1b = (const float*)d_in[8];
    const float* c2w = (const float*)d_in[9];
    const float* c2b = (const float*)d_in[10];
    const float* bn2g = (const float*)d_in[11];
    const float* bn2b = (const float*)d_in[12];
    const float* wihf = (const float*)d_in[13];
    const float* whhf = (const float*)d_in[14];
    const float* bihf = (const float*)d_in[15];
    const float* bhhf = (const float*)d_in[16];
    const float* wihb = (const float*)d_in[17];
    const float* whhb = (const float*)d_in[18];
    const float* bihb = (const float*)d_in[19];
    const float* bhhb = (const float*)d_in[20];
    const float* dwih = (const float*)d_in[21];
    const float* dwhh = (const float*)d_in[22];
    const float* dbih = (const float*)d_in[23];
    const float* dbhh = (const float*)d_in[24];
    const float* projw = (const float*)d_in[25];
    const float* projb = (const float*)d_in[26];
    const float* gatew = (const float*)d_in[27];
    const float* gateb = (const float*)d_in[28];
    float* out = (float*)d_out;
    char* ws = (char*)d_ws;

    unsigned* flagE = (unsigned*)(ws + WS_FLAGE);
    unsigned* flagD = (unsigned*)(ws + WS_FLAGD);
    half_t* henc = (half_t*)(ws + WS_HENC);
    half_t* hd = (half_t*)(ws + WS_HD);
    half_t* bufX = (half_t*)(ws + WS_BUFX);
    half_t* bufY = (half_t*)(ws + WS_BUFY);
    float* convf = (float*)(ws + WS_CONVF);
    half_t* weff = (half_t*)(ws + WS_WEFF);
    half_t* w0 = (half_t*)(ws + WS_W0);
    half_t* wp1 = (half_t*)(ws + WS_WP1);
    half_t* wp2 = (half_t*)(ws + WS_WP2);
    float* meanb = (float*)(ws + WS_MEAN);
    float* rstdb = (float*)(ws + WS_RSTD);
    half_t* wihp = (half_t*)(ws + WS_WIHP);
    half_t* whhp = (half_t*)(ws + WS_WHHP);
    float* bsum = (float*)(ws + WS_BSUM);
    float* beff = (float*)(ws + WS_BEFF);
    float* b0 = (float*)(ws + WS_B0);
    half_t* projwb = (half_t*)(ws + WS_PROJW);
    half_t* projg = (half_t*)(ws + WS_PROJG);
    float* cel = (float*)(ws + WS_CEL);

    // zero flag arrays + encoder ring slot 0 (re-done every launch/replay)
    hipMemsetAsync(d_ws, 0, (size_t)WS_ZERO_BYTES, stream);

    // front-end
    k_embed<<<NROWS, 256, 0, stream>>>(x, emb, bufX);
    k_packconvw<<<(3 * EE * EE + 255) / 256, 256, 0, stream>>>(c1w, wp1);
    k_conv<<<dim3(128, 32), 256, 0, stream>>>(bufX, wp1, c1b, convf);
    k_bnstats<<<EE, 256, 0, stream>>>(convf, meanb, rstdb);
    k_bnapply<<<(NROWS * EE) / 256, 256, 0, stream>>>(convf, meanb, rstdb, bn1g, bn1b, bufY);
    k_packconvw<<<(3 * EE * EE + 255) / 256, 256, 0, stream>>>(c2w, wp2);
    k_conv<<<dim3(128, 32), 256, 0, stream>>>(bufY, wp2, c2b, convf);
    k_bnstats<<<EE, 256, 0, stream>>>(convf, meanb, rstdb);
    k_bnapply<<<(NROWS * EE) / 256, 256, 0, stream>>>(convf, meanb, rstdb, bn2g, bn2b, bufX);

    // encoder weight prep
    const int encTot = 2048 * 512;
    k_packrec<<<(encTot + 255) / 256, 256, 0, stream>>>(wihf, wihp, HH, 9, encTot);
    k_packrec<<<(encTot + 255) / 256, 256, 0, stream>>>(wihb, wihp + encTot, HH, 9, encTot);
    k_packrec<<<(encTot + 255) / 256, 256, 0, stream>>>(whhf, whhp, HH, 9, encTot);
    k_packrec<<<(encTot + 255) / 256, 256, 0, stream>>>(whhb, whhp + encTot, HH, 9, encTot);
    k_bsumenc<<<16, 256, 0, stream>>>(bihf, bhhf, bihb, bhhb, bsum);

    // persistent bidirectional encoder (writes hd ring slot 0 + cel)
    k_enc<<<64, 512, 0, stream>>>(bufX, wihp, whhp, bsum, tlens, henc, hd, cel, flagE);

    // decoder weight prep (into retired convf region)
    k_weff<<<dim3(4096, 4), 256, 0, stream>>>(dwhh, dwih, projw, weff, w0);
    k_bdec<<<16, 256, 0, stream>>>(dbih, dbhh, dwih, projb, beff, b0);
    k_cast<<<(MM * DD + 255) / 256, 256, 0, stream>>>(projw, projwb, MM * DD);
    k_projg<<<(16 * DD + 255) / 256, 256, 0, stream>>>(gatew, projg);

    // persistent decoder
    k_dec<<<64, 512, 0, stream>>>(weff, w0, beff, b0, projwb, projg, projb, gateb,
                                  mlens, cel, hd, out, flagD);

    // mask output
    k_mask<<<(B_ * TMEL + 255) / 256, 256, 0, stream>>>(mlens, out);

    (void)in_sizes; (void)n_in; (void)out_size; (void)ws_size;
}

// Round 2
// 14698.102 us; speedup vs baseline: 1.1091x; 1.1091x over previous
//
#include <hip/hip_runtime.h>

// ---------------------------------------------------------------------------
// TTS forward on MI355X.
//   embed -> conv1(+BN+ReLU) -> conv2(+BN+ReLU) -> persistent biLSTM encoder
//   -> W_eff fold (decoder input GEMM folded into recurrent weights)
//   -> persistent 800-step decoder LSTM (fused mel/gate output duty)
// Round 5: write-fan-out mailbox sync. Each consumer block polls a PRIVATE
// mailbox (no cross-block read fan-in on hot lines); each producer wave,
// after vmcnt(0) ack of its sc0/sc1 h stores, fans its monotonic step
// counter out to every consumer's mailbox (one-shot 4B stores). Data ring
// (never-reused addresses, plain cached consumer loads) unchanged.
// ---------------------------------------------------------------------------

typedef float f4 __attribute__((ext_vector_type(4)));
typedef _Float16 h8 __attribute__((ext_vector_type(8)));
typedef _Float16 half_t;
typedef unsigned long long u64;

#define B_    32
#define LTXT  256
#define TMEL  800
#define EE    512
#define HH    512
#define DD    1024
#define MM    128
#define NROWS 8192          // B_*LTXT
#define GATE_OFF 3276800    // B_*TMEL*MM
#define MASK_OFF 3302400    // + B_*TMEL

#define RING_D 801          // decoder h ring slots (never reused in 800 steps)
#define RING_E 257          // encoder h ring slots
#define HOP    13           // slot hop stride (coprime with both rings)

// workspace offsets (bytes)
#define WS_MBE        0ull             // enc mailboxes: 2*32 consumers x 64 u32 = 16 KiB
#define WS_MBD        16384ull         // dec mailboxes: 64 consumers x 128 u32 = 32 KiB
#define WS_HENC       49152ull         // RING_E * 65536
#define WS_ZERO_BYTES 114688ull        // mailboxes + henc slot 0
#define WS_HD         16891904ull      // RING_D * 65536
#define WS_BUFX       69386240ull      // 8 MiB
#define WS_BUFY       77774848ull      // 8 MiB
#define WS_CONVF      86163456ull      // 16 MiB (reused by WEFF/W0 after convs)
#define WS_WEFF       86163456ull
#define WS_W0         94552064ull
#define WS_WP1        102940672ull
#define WS_WP2        104513536ull
#define WS_WIHP       106086400ull     // 4 MiB
#define WS_WHHP       110280704ull     // 4 MiB
#define WS_BSUM       114475008ull
#define WS_BEFF       114491392ull
#define WS_B0         114507776ull
#define WS_MEAN       114524160ull
#define WS_RSTD       114526208ull
#define WS_PROJW      114528256ull
#define WS_PROJG      114790400ull
#define WS_CEL        114823168ull
// total ~114.95 MB

__device__ __forceinline__ float sigm(float x) { return 1.f / (1.f + __expf(-x)); }
__device__ __forceinline__ float tanh_f(float x) {
    float e = __expf(2.f * x);
    return 1.f - 2.f / (e + 1.f);
}

// write-through store (bypass L1/L2, land at L3 coherence point), non-atomic
__device__ __forceinline__ void st_wt64(void* p, u64 v) {
    asm volatile("global_store_dwordx2 %0, %1, off sc0 sc1" :: "v"(p), "v"(v) : "memory");
}

// ---------------- small prep kernels ----------------

__global__ void k_embed(const int* __restrict__ x, const float* __restrict__ emb,
                        half_t* __restrict__ out) {
    int row = blockIdx.x;
    int tok = x[row];
    const float* e = emb + (size_t)tok * EE;
    half_t* o = out + (size_t)row * EE;
    for (int c = threadIdx.x; c < EE; c += blockDim.x) o[c] = (half_t)e[c];
}

__global__ void k_packconvw(const float* __restrict__ w, half_t* __restrict__ wp) {
    int idx = blockIdx.x * 256 + threadIdx.x;
    if (idx >= 3 * EE * EE) return;
    int s = idx / (EE * EE);
    int rem = idx - s * EE * EE;
    int eo = rem >> 9, ei = rem & 511;
    wp[idx] = (half_t)w[(size_t)eo * (EE * 3) + ei * 3 + s];
}

__global__ __launch_bounds__(256) void k_conv(const half_t* __restrict__ A,
                                              const half_t* __restrict__ Wp,
                                              const float* __restrict__ bias,
                                              float* __restrict__ out) {
    const int nt = blockIdx.x, et = blockIdx.y;
    const int tid = threadIdx.x;
    const int wv = tid >> 6, l = tid & 63, quad = l >> 4, lo = l & 15;
    const int rowA = nt * 64 + wv * 16 + lo;
    const int eo = et * 16 + lo;
    f4 acc = {0.f, 0.f, 0.f, 0.f};
    for (int s = 0; s < 3; ++s) {
        int lsp = (rowA & 255) + s - 1;
        bool valid = (lsp >= 0) && (lsp < 256);
        int rs = rowA + s - 1;
        rs = rs < 0 ? 0 : (rs > NROWS - 1 ? NROWS - 1 : rs);
        const half_t* ab = A + (size_t)rs * EE;
        const half_t* wb = Wp + ((size_t)s * EE + eo) * EE;
#pragma unroll 4
        for (int ks = 0; ks < 16; ++ks) {
            h8 a = {0, 0, 0, 0, 0, 0, 0, 0};
            if (valid) a = *(const h8*)(ab + ks * 32 + quad * 8);
            h8 b = *(const h8*)(wb + ks * 32 + quad * 8);
            acc = __builtin_amdgcn_mfma_f32_16x16x32_f16(a, b, acc, 0, 0, 0);
        }
    }
    const int orow = nt * 64 + wv * 16 + quad * 4;
    const float bv = bias[eo];
#pragma unroll
    for (int r = 0; r < 4; ++r) out[(size_t)(orow + r) * EE + eo] = acc[r] + bv;
}

__global__ __launch_bounds__(256) void k_bnstats(const float* __restrict__ x,
                                                 float* __restrict__ mean,
                                                 float* __restrict__ rstd) {
    const int c = blockIdx.x;
    float s = 0.f, ss = 0.f;
    for (int n = threadIdx.x; n < NROWS; n += 256) {
        float v = x[(size_t)n * EE + c];
        s += v; ss += v * v;
    }
#pragma unroll
    for (int off = 32; off > 0; off >>= 1) { s += __shfl_down(s, off); ss += __shfl_down(ss, off); }
    __shared__ float as[4], ass[4];
    int wv = threadIdx.x >> 6;
    if ((threadIdx.x & 63) == 0) { as[wv] = s; ass[wv] = ss; }
    __syncthreads();
    if (threadIdx.x == 0) {
        float S = as[0] + as[1] + as[2] + as[3];
        float SS = ass[0] + ass[1] + ass[2] + ass[3];
        float m = S / (float)NROWS;
        float var = SS / (float)NROWS - m * m;
        mean[c] = m;
        rstd[c] = rsqrtf(var + 1e-5f);
    }
}

__global__ void k_bnapply(const float* __restrict__ x, const float* __restrict__ mean,
                          const float* __restrict__ rstd, const float* __restrict__ g,
                          const float* __restrict__ beta, half_t* __restrict__ out) {
    int idx = blockIdx.x * 256 + threadIdx.x;
    if (idx >= NROWS * EE) return;
    int c = idx & (EE - 1);
    float v = (x[idx] - mean[c]) * rstd[c] * g[c] + beta[c];
    out[idx] = (half_t)(v > 0.f ? v : 0.f);
}

__global__ void k_packrec(const float* __restrict__ src, half_t* __restrict__ dst,
                          int Hdim, int kshift, int total) {
    int idx = blockIdx.x * 256 + threadIdx.x;
    if (idx >= total) return;
    int p = idx >> kshift;
    int k = idx & ((1 << kshift) - 1);
    int he = p >> 2, g = p & 3;
    dst[idx] = (half_t)src[((size_t)g * Hdim + he) * (size_t)(1 << kshift) + k];
}

__global__ void k_bsumenc(const float* __restrict__ bf, const float* __restrict__ bhf,
                          const float* __restrict__ bb, const float* __restrict__ bhb,
                          float* __restrict__ bsum) {
    int p = blockIdx.x * 256 + threadIdx.x;
    if (p >= 4096) return;
    int dir = p >> 11, pp = p & 2047;
    int he = pp >> 2, g = pp & 3;
    int row = g * HH + he;
    bsum[p] = dir ? (bb[row] + bhb[row]) : (bf[row] + bhf[row]);
}

__global__ __launch_bounds__(256) void k_weff(const float* __restrict__ dwhh,
                                              const float* __restrict__ dwih,
                                              const float* __restrict__ projw,
                                              half_t* __restrict__ weff,
                                              half_t* __restrict__ w0) {
    int row = blockIdx.x;
    int k = blockIdx.y * 256 + threadIdx.x;
    float v = dwhh[(size_t)row * DD + k];
    float acc = v;
    for (int m = 0; m < MM; ++m) acc += dwih[(size_t)row * MM + m] * projw[(size_t)m * DD + k];
    int p = ((row & (DD - 1)) << 2) | (row >> 10);
    weff[(size_t)p * DD + k] = (half_t)acc;
    w0[(size_t)p * DD + k] = (half_t)v;
}

__global__ void k_bdec(const float* __restrict__ dbih, const float* __restrict__ dbhh,
                       const float* __restrict__ dwih, const float* __restrict__ projb,
                       float* __restrict__ beff, float* __restrict__ b0) {
    int p = blockIdx.x * 256 + threadIdx.x;
    if (p >= 4096) return;
    int he = p >> 2, g = p & 3;
    int row = g * DD + he;
    float bb = dbih[row] + dbhh[row];
    float acc = bb;
    for (int m = 0; m < MM; ++m) acc += dwih[(size_t)row * MM + m] * projb[m];
    b0[p] = bb;
    beff[p] = acc;
}

__global__ void k_cast(const float* __restrict__ src, half_t* __restrict__ dst, int n) {
    int idx = blockIdx.x * 256 + threadIdx.x;
    if (idx < n) dst[idx] = (half_t)src[idx];
}

__global__ void k_projg(const float* __restrict__ gw, half_t* __restrict__ pg) {
    int idx = blockIdx.x * 256 + threadIdx.x;
    if (idx >= 16 * DD) return;
    int row = idx >> 10, k = idx & (DD - 1);
    pg[idx] = (half_t)(row == 0 ? gw[k] : 0.f);
}

__global__ void k_mask(const int* __restrict__ lens, float* __restrict__ out) {
    int idx = blockIdx.x * 256 + threadIdx.x;
    if (idx >= B_ * TMEL) return;
    int b = idx / TMEL, t = idx - b * TMEL;
    out[MASK_OFF + idx] = (t > lens[b]) ? 1.f : 0.f;
}

// ---------------- persistent bidirectional encoder LSTM ----------------
// 64 blocks x 512 thr. dir=j>>5 (independent mailbox ranges), sub=j&31 owns
// 16 h-elems. h ring: slot sp read, slot sn written (never-reused addresses).
// Sync: producer wave w, after vmcnt(0) ack of its data stores, fans value
// (t+1) out to all 32 same-dir consumers' private mailboxes (one 4B store
// per consumer). Consumer polls ONLY its own 64-flag mailbox (2 lines).
__global__ __launch_bounds__(512) void k_enc(const half_t* __restrict__ X,
                                             const half_t* __restrict__ wihp,
                                             const half_t* __restrict__ whhp,
                                             const float* __restrict__ bsum,
                                             const int* __restrict__ lens,
                                             half_t* __restrict__ henc,   // ring [RING_E][2][32][512]
                                             half_t* __restrict__ hd0,    // ring slot 0: [32][1024]
                                             float* __restrict__ cel,     // [32][1024]
                                             unsigned* __restrict__ mbE) { // [2*32 consumers][64]
    const int j = blockIdx.x;
    const int dir = j >> 5, sub = j & 31;
    const int tid = threadIdx.x;
    const int wv = tid >> 6, l = tid & 63, quad = l >> 4, lo = l & 15;
    const int rg = wv >> 1, bh = wv & 1;
    const int bfr = bh * 16 + lo;
    const int ue = tid >> 5, ub = tid & 31;

    __shared__ half_t s_hd[32 * 520];
    __shared__ float s_g[32][65];
    __shared__ float s_c[16][32];
    __shared__ float s_h[16][32];
    __shared__ half_t s_hh[16][32];
    __shared__ int s_len[32];

    if (tid < 32) s_len[tid] = lens[tid];
    s_c[ue][ub] = 0.f;
    s_h[ue][ub] = 0.f;

    const int pr = dir * 2048 + sub * 64 + rg * 16 + lo;
    const half_t* wih_b = wihp + (size_t)pr * 512;
    const half_t* whh_b = whhp + (size_t)pr * 512;
    const float bias_n = bsum[pr];

    int sp = 0, sn = HOP;
    __syncthreads();

    for (int t = 0; t < 256; ++t) {
        // wait for all producers of slot sp via private mailbox (slot 0 => skip)
        if (t > 0) {
            if (tid < 64) {
                const unsigned want = (unsigned)t;
                const unsigned* fp = mbE + (size_t)(dir * 32 + sub) * 64 + tid;
                while (__hip_atomic_load(fp, __ATOMIC_RELAXED, __HIP_MEMORY_SCOPE_AGENT) < want)
                    __builtin_amdgcn_s_sleep(1);
            }
            __syncthreads();
        }

        // issue h-slot coop loads (fresh cold addresses -> L3)
        const half_t* src = henc + (size_t)sp * 32768 + (size_t)dir * 16384;
        h8 tmp0 = *(const h8*)(src + (size_t)(tid + 0 * 512) * 8);
        h8 tmp1 = *(const h8*)(src + (size_t)(tid + 1 * 512) * 8);
        h8 tmp2 = *(const h8*)(src + (size_t)(tid + 2 * 512) * 8);
        h8 tmp3 = *(const h8*)(src + (size_t)(tid + 3 * 512) * 8);

        // x-part MFMA overlaps the h loads
        const int lb = s_len[bfr];
        int tt = (dir == 0) ? t : (lb - 1 - t);
        tt = tt < 0 ? 0 : tt;
        const half_t* xr = X + ((size_t)bfr * 256 + tt) * 512;
        f4 accA = {0.f, 0.f, 0.f, 0.f}, accB = {0.f, 0.f, 0.f, 0.f};
#pragma unroll 4
        for (int ks = 0; ks < 16; ++ks) {
            h8 a = *(const h8*)(xr + ks * 32 + quad * 8);
            h8 b = *(const h8*)(wih_b + ks * 32 + quad * 8);
            accA = __builtin_amdgcn_mfma_f32_16x16x32_f16(a, b, accA, 0, 0, 0);
        }

        // stage h into LDS
        {
            int c0 = tid;
            *(h8*)(s_hd + (size_t)(c0 >> 6) * 520 + (c0 & 63) * 8) = tmp0;
            int c1 = tid + 512;
            *(h8*)(s_hd + (size_t)(c1 >> 6) * 520 + (c1 & 63) * 8) = tmp1;
            int c2 = tid + 1024;
            *(h8*)(s_hd + (size_t)(c2 >> 6) * 520 + (c2 & 63) * 8) = tmp2;
            int c3 = tid + 1536;
            *(h8*)(s_hd + (size_t)(c3 >> 6) * 520 + (c3 & 63) * 8) = tmp3;
        }
        __syncthreads();

#pragma unroll 4
        for (int ks = 0; ks < 16; ++ks) {
            h8 a = *(const h8*)(s_hd + (size_t)bfr * 520 + ks * 32 + quad * 8);
            h8 b = *(const h8*)(whh_b + ks * 32 + quad * 8);
            accB = __builtin_amdgcn_mfma_f32_16x16x32_f16(a, b, accB, 0, 0, 0);
        }
        const int bm = bh * 16 + quad * 4, cm = rg * 16 + lo;
#pragma unroll
        for (int r = 0; r < 4; ++r) s_g[bm + r][cm] = accA[r] + accB[r] + bias_n;
        __syncthreads();
        {
            float gi = s_g[ub][ue * 4 + 0], gf = s_g[ub][ue * 4 + 1];
            float gg = s_g[ub][ue * 4 + 2], go = s_g[ub][ue * 4 + 3];
            float cn = sigm(gf) * s_c[ue][ub] + sigm(gi) * tanh_f(gg);
            float hn = sigm(go) * tanh_f(cn);
            if (t < s_len[ub]) { s_c[ue][ub] = cn; s_h[ue][ub] = hn; }
            s_hh[ue][ub] = (half_t)s_h[ue][ub];
        }
        __syncthreads();
        if (tid < 128 && t < 255) {
            int eq = tid >> 5, b2 = tid & 31;
            union { half_t h[4]; u64 u; } pk;
            pk.h[0] = s_hh[eq * 4 + 0][b2]; pk.h[1] = s_hh[eq * 4 + 1][b2];
            pk.h[2] = s_hh[eq * 4 + 2][b2]; pk.h[3] = s_hh[eq * 4 + 3][b2];
            st_wt64(henc + (size_t)sn * 32768 + (size_t)dir * 16384
                    + (size_t)b2 * 512 + sub * 16 + eq * 4, pk.u);
            // per-wave ack of own data stores, then fan out this wave's flag
            asm volatile("s_waitcnt vmcnt(0)");
            {
                int w = tid >> 6, cl = tid & 63;
                if (cl < 32)
                    __hip_atomic_store(mbE + ((size_t)(dir * 32 + cl) * 64 + sub * 2 + w),
                                       (unsigned)(t + 1), __ATOMIC_RELAXED,
                                       __HIP_MEMORY_SCOPE_AGENT);
            }
        }
        if (t < 255) { sp = sn; sn += HOP; if (sn >= RING_E) sn -= RING_E; }
    }
    hd0[(size_t)ub * 1024 + dir * 512 + sub * 16 + ue] = (half_t)s_h[ue][ub];
    cel[(size_t)ub * 1024 + dir * 512 + sub * 16 + ue] = s_c[ue][ub];
}

// ---------------- persistent decoder LSTM ----------------
// 64 blocks x 512 thr, block j owns h-elems [16j,16j+16). h ring slots hop by
// HOP mod RING_D; slot 0 = encoder final hid. Mailbox sync: producer wave w
// fans value t out to all 64 consumers' private mailboxes after vmcnt(0)
// ack; consumer polls ONLY its own 128-flag mailbox (4 lines).
__global__ __launch_bounds__(512) void k_dec(const half_t* __restrict__ Weff,
                                             const half_t* __restrict__ W0,
                                             const float* __restrict__ beff,
                                             const float* __restrict__ b0,
                                             const half_t* __restrict__ projwb,
                                             const half_t* __restrict__ projg,
                                             const float* __restrict__ projb,
                                             const float* __restrict__ gateb,
                                             const int* __restrict__ mlens,
                                             const float* __restrict__ cel,
                                             half_t* __restrict__ hd,   // ring [RING_D][32][1024]
                                             float* __restrict__ out,
                                             unsigned* __restrict__ mbD) { // [64 consumers][128]
    const int j = blockIdx.x;
    const int tid = threadIdx.x;
    const int wv = tid >> 6, l = tid & 63, quad = l >> 4, lo = l & 15;
    const int rg = wv >> 1, bh = wv & 1;
    const int bfr = bh * 16 + lo;
    const int ue = tid >> 5, ub = tid & 31;

    __shared__ half_t s_hd[32 * 1032];
    __shared__ float s_g[32][65];
    __shared__ float s_c[16][32];
    __shared__ half_t s_hh[16][32];
    __shared__ int s_len[32];

    if (tid < 32) s_len[tid] = mlens[tid];
    s_c[ue][ub] = cel[(size_t)ub * 1024 + j * 16 + ue];
    const int pr = j * 64 + rg * 16 + lo;
    const float biasE = beff[pr], bias0 = b0[pr];
    const bool meld = (j < 8), gated = (j == 8);
    const bool duty = (meld || gated) && (rg == 0);
    const half_t* pw = nullptr;
    float biasP = 0.f;
    if (duty) {
        pw = meld ? (projwb + (size_t)(j * 16 + lo) * 1024) : (projg + (size_t)lo * 1024);
        biasP = meld ? projb[j * 16 + lo] : gateb[0];
    }
    const half_t* wbE = Weff + (size_t)pr * 1024;
    const half_t* wb0 = W0 + (size_t)pr * 1024;

    int sp = 0, sn = HOP;
    __syncthreads();

    for (int t = 1; t <= TMEL; ++t) {
        // wait for all producers of slot sp via private mailbox (t==1: slot 0
        // from k_enc, visible via kernel-boundary coherence => skip)
        if (t > 1) {
            if (tid < 128) {
                const unsigned want = (unsigned)(t - 1);
                const unsigned* fp = mbD + (size_t)j * 128 + tid;
                while (__hip_atomic_load(fp, __ATOMIC_RELAXED, __HIP_MEMORY_SCOPE_AGENT) < want)
                    __builtin_amdgcn_s_sleep(1);
            }
            __syncthreads();
        }

        // cooperative load of h slot (fresh cold addresses)
        const half_t* src = hd + (size_t)sp * 32768;
        {
            h8 tp[8];
#pragma unroll
            for (int i = 0; i < 8; ++i)
                tp[i] = *(const h8*)(src + (size_t)(tid + i * 512) * 8);
#pragma unroll
            for (int i = 0; i < 8; ++i) {
                int c = tid + i * 512;
                *(h8*)(s_hd + (size_t)(c >> 7) * 1032 + (c & 127) * 8) = tp[i];
            }
        }
        __syncthreads();

        const half_t* wb = (t == 1) ? wb0 : wbE;
        const half_t* ar = s_hd + (size_t)bfr * 1032 + quad * 8;
        f4 acc = {0.f, 0.f, 0.f, 0.f}, acc2 = {0.f, 0.f, 0.f, 0.f};
        if (duty && t >= 2) {
            f4 accm = {0.f, 0.f, 0.f, 0.f}, accm2 = {0.f, 0.f, 0.f, 0.f};
#pragma unroll 8
            for (int ks = 0; ks < 32; ks += 2) {
                h8 a0 = *(const h8*)(ar + ks * 32);
                h8 a1 = *(const h8*)(ar + ks * 32 + 32);
                acc = __builtin_amdgcn_mfma_f32_16x16x32_f16(a0, *(const h8*)(wb + ks * 32 + quad * 8), acc, 0, 0, 0);
                acc2 = __builtin_amdgcn_mfma_f32_16x16x32_f16(a1, *(const h8*)(wb + ks * 32 + 32 + quad * 8), acc2, 0, 0, 0);
                accm = __builtin_amdgcn_mfma_f32_16x16x32_f16(a0, *(const h8*)(pw + ks * 32 + quad * 8), accm, 0, 0, 0);
                accm2 = __builtin_amdgcn_mfma_f32_16x16x32_f16(a1, *(const h8*)(pw + ks * 32 + 32 + quad * 8), accm2, 0, 0, 0);
            }
            accm[0] += accm2[0]; accm[1] += accm2[1]; accm[2] += accm2[2]; accm[3] += accm2[3];
            const int pos = t - 2;
            if (meld) {
#pragma unroll
                for (int r = 0; r < 4; ++r) {
                    int b = bh * 16 + quad * 4 + r;
                    float v = accm[r] + biasP;
                    if (pos > s_len[b]) v = 0.f;
                    __builtin_nontemporal_store(v,
                        &out[(size_t)b * (TMEL * MM) + (size_t)pos * MM + j * 16 + lo]);
                }
            } else if (lo == 0) {
#pragma unroll
                for (int r = 0; r < 4; ++r) {
                    int b = bh * 16 + quad * 4 + r;
                    float v = accm[r] + biasP;
                    if (pos > s_len[b]) v = 1000.f;
                    __builtin_nontemporal_store(v, &out[GATE_OFF + (size_t)b * TMEL + pos]);
                }
            }
        } else {
#pragma unroll 8
            for (int ks = 0; ks < 32; ks += 2) {
                h8 a0 = *(const h8*)(ar + ks * 32);
                h8 a1 = *(const h8*)(ar + ks * 32 + 32);
                acc = __builtin_amdgcn_mfma_f32_16x16x32_f16(a0, *(const h8*)(wb + ks * 32 + quad * 8), acc, 0, 0, 0);
                acc2 = __builtin_amdgcn_mfma_f32_16x16x32_f16(a1, *(const h8*)(wb + ks * 32 + 32 + quad * 8), acc2, 0, 0, 0);
            }
        }
        const float bn = (t == 1) ? bias0 : biasE;
        const int bm = bh * 16 + quad * 4, cm = rg * 16 + lo;
#pragma unroll
        for (int r = 0; r < 4; ++r) s_g[bm + r][cm] = acc[r] + acc2[r] + bn;
        __syncthreads();
        {
            float gi = s_g[ub][ue * 4 + 0], gf = s_g[ub][ue * 4 + 1];
            float gg = s_g[ub][ue * 4 + 2], go = s_g[ub][ue * 4 + 3];
            float cn = sigm(gf) * s_c[ue][ub] + sigm(gi) * tanh_f(gg);
            s_c[ue][ub] = cn;
            s_hh[ue][ub] = (half_t)(sigm(go) * tanh_f(cn));
        }
        __syncthreads();
        if (tid < 128) {
            int eq = tid >> 5, b2 = tid & 31;
            union { half_t h[4]; u64 u; } pk;
            pk.h[0] = s_hh[eq * 4 + 0][b2]; pk.h[1] = s_hh[eq * 4 + 1][b2];
            pk.h[2] = s_hh[eq * 4 + 2][b2]; pk.h[3] = s_hh[eq * 4 + 3][b2];
            st_wt64(hd + (size_t)sn * 32768 + (size_t)b2 * 1024 + j * 16 + eq * 4, pk.u);
            // per-wave ack of own data stores, then fan out this wave's flag
            asm volatile("s_waitcnt vmcnt(0)");
            {
                int w = tid >> 6, cl = tid & 63;
                __hip_atomic_store(mbD + ((size_t)cl * 128 + j * 2 + w),
                                   (unsigned)t, __ATOMIC_RELAXED,
                                   __HIP_MEMORY_SCOPE_AGENT);
            }
        }
        sp = sn; sn += HOP; if (sn >= RING_D) sn -= RING_D;
    }
    // epilogue: outputs for pos 799 from h_800 (slot sp)
    if (meld || gated) {
        if (tid < 128) {
            const unsigned* fp = mbD + (size_t)j * 128 + tid;
            while (__hip_atomic_load(fp, __ATOMIC_RELAXED, __HIP_MEMORY_SCOPE_AGENT) < (unsigned)TMEL)
                __builtin_amdgcn_s_sleep(1);
        }
        __syncthreads();
        const half_t* src = hd + (size_t)sp * 32768;
        {
            h8 tp[8];
#pragma unroll
            for (int i = 0; i < 8; ++i)
                tp[i] = *(const h8*)(src + (size_t)(tid + i * 512) * 8);
#pragma unroll
            for (int i = 0; i < 8; ++i) {
                int c = tid + i * 512;
                *(h8*)(s_hd + (size_t)(c >> 7) * 1032 + (c & 127) * 8) = tp[i];
            }
        }
        __syncthreads();
        if (duty) {
            const half_t* ar = s_hd + (size_t)bfr * 1032 + quad * 8;
            f4 accm = {0.f, 0.f, 0.f, 0.f};
#pragma unroll 4
            for (int ks = 0; ks < 32; ++ks) {
                h8 a = *(const h8*)(ar + ks * 32);
                accm = __builtin_amdgcn_mfma_f32_16x16x32_f16(a, *(const h8*)(pw + ks * 32 + quad * 8), accm, 0, 0, 0);
            }
            if (meld) {
#pragma unroll
                for (int r = 0; r < 4; ++r) {
                    int b = bh * 16 + quad * 4 + r;
                    float v = accm[r] + biasP;
                    if (799 > s_len[b]) v = 0.f;
                    out[(size_t)b * (TMEL * MM) + (size_t)799 * MM + j * 16 + lo] = v;
                }
            } else if (lo == 0) {
#pragma unroll
                for (int r = 0; r < 4; ++r) {
                    int b = bh * 16 + quad * 4 + r;
                    float v = accm[r] + biasP;
                    if (799 > s_len[b]) v = 1000.f;
                    out[GATE_OFF + (size_t)b * TMEL + 799] = v;
                }
            }
        }
    }
}

// ---------------------------------------------------------------------------

extern "C" void kernel_launch(void* const* d_in, const int* in_sizes, int n_in,
                              void* d_out, int out_size, void* d_ws, size_t ws_size,
                              hipStream_t stream) {
    const int* x = (const int*)d_in[0];
    const int* tlens = (const int*)d_in[1];
    const int* mlens = (const int*)d_in[3];
    const float* emb = (const float*)d_in[4];
    const float* c1w = (const float*)d_in[5];
    const float* c1b = (const float*)d_in[6];
    const float* bn1g = (const float*)d_in[7];
    const float* bn1b = (const float*)d_in[8];
    const float* c2w = (const float*)d_in[9];
    const float* c2b = (const float*)d_in[10];
    const float* bn2g = (const float*)d_in[11];
    const float* bn2b = (const float*)d_in[12];
    const float* wihf = (const float*)d_in[13];
    const float* whhf = (const float*)d_in[14];
    const float* bihf = (const float*)d_in[15];
    const float* bhhf = (const float*)d_in[16];
    const float* wihb = (const float*)d_in[17];
    const float* whhb = (const float*)d_in[18];
    const float* bihb = (const float*)d_in[19];
    const float* bhhb = (const float*)d_in[20];
    const float* dwih = (const float*)d_in[21];
    const float* dwhh = (const float*)d_in[22];
    const float* dbih = (const float*)d_in[23];
    const float* dbhh = (const float*)d_in[24];
    const float* projw = (const float*)d_in[25];
    const float* projb = (const float*)d_in[26];
    const float* gatew = (const float*)d_in[27];
    const float* gateb = (const float*)d_in[28];
    float* out = (float*)d_out;
    char* ws = (char*)d_ws;

    unsigned* mbE = (unsigned*)(ws + WS_MBE);
    unsigned* mbD = (unsigned*)(ws + WS_MBD);
    half_t* henc = (half_t*)(ws + WS_HENC);
    half_t* hd = (half_t*)(ws + WS_HD);
    half_t* bufX = (half_t*)(ws + WS_BUFX);
    half_t* bufY = (half_t*)(ws + WS_BUFY);
    float* convf = (float*)(ws + WS_CONVF);
    half_t* weff = (half_t*)(ws + WS_WEFF);
    half_t* w0 = (half_t*)(ws + WS_W0);
    half_t* wp1 = (half_t*)(ws + WS_WP1);
    half_t* wp2 = (half_t*)(ws + WS_WP2);
    float* meanb = (float*)(ws + WS_MEAN);
    float* rstdb = (float*)(ws + WS_RSTD);
    half_t* wihp = (half_t*)(ws + WS_WIHP);
    half_t* whhp = (half_t*)(ws + WS_WHHP);
    float* bsum = (float*)(ws + WS_BSUM);
    float* beff = (float*)(ws + WS_BEFF);
    float* b0 = (float*)(ws + WS_B0);
    half_t* projwb = (half_t*)(ws + WS_PROJW);
    half_t* projg = (half_t*)(ws + WS_PROJG);
    float* cel = (float*)(ws + WS_CEL);

    // zero mailboxes + encoder ring slot 0 (re-done every launch/replay)
    hipMemsetAsync(d_ws, 0, (size_t)WS_ZERO_BYTES, stream);

    // front-end
    k_embed<<<NROWS, 256, 0, stream>>>(x, emb, bufX);
    k_packconvw<<<(3 * EE * EE + 255) / 256, 256, 0, stream>>>(c1w, wp1);
    k_conv<<<dim3(128, 32), 256, 0, stream>>>(bufX, wp1, c1b, convf);
    k_bnstats<<<EE, 256, 0, stream>>>(convf, meanb, rstdb);
    k_bnapply<<<(NROWS * EE) / 256, 256, 0, stream>>>(convf, meanb, rstdb, bn1g, bn1b, bufY);
    k_packconvw<<<(3 * EE * EE + 255) / 256, 256, 0, stream>>>(c2w, wp2);
    k_conv<<<dim3(128, 32), 256, 0, stream>>>(bufY, wp2, c2b, convf);
    k_bnstats<<<EE, 256, 0, stream>>>(convf, meanb, rstdb);
    k_bnapply<<<(NROWS * EE) / 256, 256, 0, stream>>>(convf, meanb, rstdb, bn2g, bn2b, bufX);

    // encoder weight prep
    const int encTot = 2048 * 512;
    k_packrec<<<(encTot + 255) / 256, 256, 0, stream>>>(wihf, wihp, HH, 9, encTot);
    k_packrec<<<(encTot + 255) / 256, 256, 0, stream>>>(wihb, wihp + encTot, HH, 9, encTot);
    k_packrec<<<(encTot + 255) / 256, 256, 0, stream>>>(whhf, whhp, HH, 9, encTot);
    k_packrec<<<(encTot + 255) / 256, 256, 0, stream>>>(whhb, whhp + encTot, HH, 9, encTot);
    k_bsumenc<<<16, 256, 0, stream>>>(bihf, bhhf, bihb, bhhb, bsum);

    // persistent bidirectional encoder (writes hd ring slot 0 + cel)
    k_enc<<<64, 512, 0, stream>>>(bufX, wihp, whhp, bsum, tlens, henc, hd, cel, mbE);

    // decoder weight prep (into retired convf region)
    k_weff<<<dim3(4096, 4), 256, 0, stream>>>(dwhh, dwih, projw, weff, w0);
    k_bdec<<<16, 256, 0, stream>>>(dbih, dbhh, dwih, projb, beff, b0);
    k_cast<<<(MM * DD + 255) / 256, 256, 0, stream>>>(projw, projwb, MM * DD);
    k_projg<<<(16 * DD + 255) / 256, 256, 0, stream>>>(gatew, projg);

    // persistent decoder
    k_dec<<<64, 512, 0, stream>>>(weff, w0, beff, b0, projwb, projg, projb, gateb,
                                  mlens, cel, hd, out, mbD);

    // mask output
    k_mask<<<(B_ * TMEL + 255) / 256, 256, 0, stream>>>(mlens, out);

    (void)in_sizes; (void)n_in; (void)out_size; (void)ws_size;
}

// Round 3
// 5149.726 us; speedup vs baseline: 3.1655x; 2.8542x over previous
//
#include <hip/hip_runtime.h>

// ---------------------------------------------------------------------------
// TTS forward on MI355X.
//   embed -> conv1(+BN+ReLU) -> conv2(+BN+ReLU) -> persistent biLSTM encoder
//   -> W_eff fold (decoder input GEMM folded into recurrent weights)
//   -> persistent 800-step decoder LSTM + lagging projection consumer blocks
// Round 6: critical-path slimming.
//   - mel/gate projection moved OFF the ring critical path into 9 dedicated
//     consumer blocks (grid 64+9) that lag behind producers harmlessly.
//   - recurrent weights live in VGPRs (filled once); per-step MFMA reads
//     only LDS + registers.
//   - single store wave, dwordx4 sc0/sc1 stores, one flag per producer,
//     poll on a non-storing wave.
// ---------------------------------------------------------------------------

typedef float f4 __attribute__((ext_vector_type(4)));
typedef _Float16 h8 __attribute__((ext_vector_type(8)));
typedef _Float16 half_t;
typedef unsigned u4 __attribute__((ext_vector_type(4)));
typedef unsigned long long u64;

#define B_    32
#define LTXT  256
#define TMEL  800
#define EE    512
#define HH    512
#define DD    1024
#define MM    128
#define NROWS 8192          // B_*LTXT
#define GATE_OFF 3276800    // B_*TMEL*MM
#define MASK_OFF 3302400    // + B_*TMEL

#define RING_D 801          // decoder h ring slots (never reused in 800 steps)
#define RING_E 257          // encoder h ring slots
#define HOP    13           // slot hop stride (coprime with both rings)

// workspace offsets (bytes)
#define WS_MBE        0ull             // enc mailboxes: 64 consumers x 64 u32 = 16 KiB
#define WS_MBD        16384ull         // dec mailboxes: 73 consumers x 64 u32 (pad 32 KiB)
#define WS_HENC       49152ull         // RING_E * 65536
#define WS_ZERO_BYTES 81920ull         // mailboxes + henc slot 0
#define WS_HD         16891904ull      // RING_D * 65536
#define WS_BUFX       69386240ull      // 8 MiB
#define WS_BUFY       77774848ull      // 8 MiB
#define WS_CONVF      86163456ull      // 16 MiB (reused by WEFF/W0 after convs)
#define WS_WEFF       86163456ull
#define WS_W0         94552064ull
#define WS_WP1        102940672ull
#define WS_WP2        104513536ull
#define WS_WIHP       106086400ull     // 4 MiB
#define WS_WHHP       110280704ull     // 4 MiB
#define WS_BSUM       114475008ull
#define WS_BEFF       114491392ull
#define WS_B0         114507776ull
#define WS_MEAN       114524160ull
#define WS_RSTD       114526208ull
#define WS_PROJW      114528256ull
#define WS_PROJG      114790400ull
#define WS_CEL        114823168ull
// total ~114.95 MB

__device__ __forceinline__ float sigm(float x) { return 1.f / (1.f + __expf(-x)); }
__device__ __forceinline__ float tanh_f(float x) {
    float e = __expf(2.f * x);
    return 1.f - 2.f / (e + 1.f);
}

// write-through 16B store (bypass L1/L2, land at L3 coherence point)
__device__ __forceinline__ void st_wt128(void* p, u4 v) {
    asm volatile("global_store_dwordx4 %0, %1, off sc0 sc1" :: "v"(p), "v"(v) : "memory");
}

// ---------------- small prep kernels ----------------

__global__ void k_embed(const int* __restrict__ x, const float* __restrict__ emb,
                        half_t* __restrict__ out) {
    int row = blockIdx.x;
    int tok = x[row];
    const float* e = emb + (size_t)tok * EE;
    half_t* o = out + (size_t)row * EE;
    for (int c = threadIdx.x; c < EE; c += blockDim.x) o[c] = (half_t)e[c];
}

__global__ void k_packconvw(const float* __restrict__ w, half_t* __restrict__ wp) {
    int idx = blockIdx.x * 256 + threadIdx.x;
    if (idx >= 3 * EE * EE) return;
    int s = idx / (EE * EE);
    int rem = idx - s * EE * EE;
    int eo = rem >> 9, ei = rem & 511;
    wp[idx] = (half_t)w[(size_t)eo * (EE * 3) + ei * 3 + s];
}

__global__ __launch_bounds__(256) void k_conv(const half_t* __restrict__ A,
                                              const half_t* __restrict__ Wp,
                                              const float* __restrict__ bias,
                                              float* __restrict__ out) {
    const int nt = blockIdx.x, et = blockIdx.y;
    const int tid = threadIdx.x;
    const int wv = tid >> 6, l = tid & 63, quad = l >> 4, lo = l & 15;
    const int rowA = nt * 64 + wv * 16 + lo;
    const int eo = et * 16 + lo;
    f4 acc = {0.f, 0.f, 0.f, 0.f};
    for (int s = 0; s < 3; ++s) {
        int lsp = (rowA & 255) + s - 1;
        bool valid = (lsp >= 0) && (lsp < 256);
        int rs = rowA + s - 1;
        rs = rs < 0 ? 0 : (rs > NROWS - 1 ? NROWS - 1 : rs);
        const half_t* ab = A + (size_t)rs * EE;
        const half_t* wb = Wp + ((size_t)s * EE + eo) * EE;
#pragma unroll 4
        for (int ks = 0; ks < 16; ++ks) {
            h8 a = {0, 0, 0, 0, 0, 0, 0, 0};
            if (valid) a = *(const h8*)(ab + ks * 32 + quad * 8);
            h8 b = *(const h8*)(wb + ks * 32 + quad * 8);
            acc = __builtin_amdgcn_mfma_f32_16x16x32_f16(a, b, acc, 0, 0, 0);
        }
    }
    const int orow = nt * 64 + wv * 16 + quad * 4;
    const float bv = bias[eo];
#pragma unroll
    for (int r = 0; r < 4; ++r) out[(size_t)(orow + r) * EE + eo] = acc[r] + bv;
}

__global__ __launch_bounds__(256) void k_bnstats(const float* __restrict__ x,
                                                 float* __restrict__ mean,
                                                 float* __restrict__ rstd) {
    const int c = blockIdx.x;
    float s = 0.f, ss = 0.f;
    for (int n = threadIdx.x; n < NROWS; n += 256) {
        float v = x[(size_t)n * EE + c];
        s += v; ss += v * v;
    }
#pragma unroll
    for (int off = 32; off > 0; off >>= 1) { s += __shfl_down(s, off); ss += __shfl_down(ss, off); }
    __shared__ float as[4], ass[4];
    int wv = threadIdx.x >> 6;
    if ((threadIdx.x & 63) == 0) { as[wv] = s; ass[wv] = ss; }
    __syncthreads();
    if (threadIdx.x == 0) {
        float S = as[0] + as[1] + as[2] + as[3];
        float SS = ass[0] + ass[1] + ass[2] + ass[3];
        float m = S / (float)NROWS;
        float var = SS / (float)NROWS - m * m;
        mean[c] = m;
        rstd[c] = rsqrtf(var + 1e-5f);
    }
}

__global__ void k_bnapply(const float* __restrict__ x, const float* __restrict__ mean,
                          const float* __restrict__ rstd, const float* __restrict__ g,
                          const float* __restrict__ beta, half_t* __restrict__ out) {
    int idx = blockIdx.x * 256 + threadIdx.x;
    if (idx >= NROWS * EE) return;
    int c = idx & (EE - 1);
    float v = (x[idx] - mean[c]) * rstd[c] * g[c] + beta[c];
    out[idx] = (half_t)(v > 0.f ? v : 0.f);
}

__global__ void k_packrec(const float* __restrict__ src, half_t* __restrict__ dst,
                          int Hdim, int kshift, int total) {
    int idx = blockIdx.x * 256 + threadIdx.x;
    if (idx >= total) return;
    int p = idx >> kshift;
    int k = idx & ((1 << kshift) - 1);
    int he = p >> 2, g = p & 3;
    dst[idx] = (half_t)src[((size_t)g * Hdim + he) * (size_t)(1 << kshift) + k];
}

__global__ void k_bsumenc(const float* __restrict__ bf, const float* __restrict__ bhf,
                          const float* __restrict__ bb, const float* __restrict__ bhb,
                          float* __restrict__ bsum) {
    int p = blockIdx.x * 256 + threadIdx.x;
    if (p >= 4096) return;
    int dir = p >> 11, pp = p & 2047;
    int he = pp >> 2, g = pp & 3;
    int row = g * HH + he;
    bsum[p] = dir ? (bb[row] + bhb[row]) : (bf[row] + bhf[row]);
}

__global__ __launch_bounds__(256) void k_weff(const float* __restrict__ dwhh,
                                              const float* __restrict__ dwih,
                                              const float* __restrict__ projw,
                                              half_t* __restrict__ weff,
                                              half_t* __restrict__ w0) {
    int row = blockIdx.x;
    int k = blockIdx.y * 256 + threadIdx.x;
    float v = dwhh[(size_t)row * DD + k];
    float acc = v;
    for (int m = 0; m < MM; ++m) acc += dwih[(size_t)row * MM + m] * projw[(size_t)m * DD + k];
    int p = ((row & (DD - 1)) << 2) | (row >> 10);
    weff[(size_t)p * DD + k] = (half_t)acc;
    w0[(size_t)p * DD + k] = (half_t)v;
}

__global__ void k_bdec(const float* __restrict__ dbih, const float* __restrict__ dbhh,
                       const float* __restrict__ dwih, const float* __restrict__ projb,
                       float* __restrict__ beff, float* __restrict__ b0) {
    int p = blockIdx.x * 256 + threadIdx.x;
    if (p >= 4096) return;
    int he = p >> 2, g = p & 3;
    int row = g * DD + he;
    float bb = dbih[row] + dbhh[row];
    float acc = bb;
    for (int m = 0; m < MM; ++m) acc += dwih[(size_t)row * MM + m] * projb[m];
    b0[p] = bb;
    beff[p] = acc;
}

__global__ void k_cast(const float* __restrict__ src, half_t* __restrict__ dst, int n) {
    int idx = blockIdx.x * 256 + threadIdx.x;
    if (idx < n) dst[idx] = (half_t)src[idx];
}

__global__ void k_projg(const float* __restrict__ gw, half_t* __restrict__ pg) {
    int idx = blockIdx.x * 256 + threadIdx.x;
    if (idx >= 16 * DD) return;
    int row = idx >> 10, k = idx & (DD - 1);
    pg[idx] = (half_t)(row == 0 ? gw[k] : 0.f);
}

__global__ void k_mask(const int* __restrict__ lens, float* __restrict__ out) {
    int idx = blockIdx.x * 256 + threadIdx.x;
    if (idx >= B_ * TMEL) return;
    int b = idx / TMEL, t = idx - b * TMEL;
    out[MASK_OFF + idx] = (t > lens[b]) ? 1.f : 0.f;
}

// ---------------- persistent bidirectional encoder LSTM ----------------
// 64 blocks x 512 thr. dir=j>>5, sub=j&31 owns 16 h-elems. Recurrent weights
// (wih, whh fragments) live in VGPRs. Store: wave 0, one dwordx4/lane,
// vmcnt(0) ack, then lanes<32 fan one flag out to same-dir consumers.
// Poll: wave 1 lanes<32 poll own private mailbox.
__global__ __launch_bounds__(512) void k_enc(const half_t* __restrict__ X,
                                             const half_t* __restrict__ wihp,
                                             const half_t* __restrict__ whhp,
                                             const float* __restrict__ bsum,
                                             const int* __restrict__ lens,
                                             half_t* __restrict__ henc,   // ring [RING_E][2][32][512]
                                             half_t* __restrict__ hd0,    // dec ring slot 0: [32][1024]
                                             float* __restrict__ cel,     // [32][1024]
                                             unsigned* __restrict__ mbE) { // [64 consumers][64]
    const int j = blockIdx.x;
    const int dir = j >> 5, sub = j & 31;
    const int tid = threadIdx.x;
    const int wv = tid >> 6, l = tid & 63, quad = l >> 4, lo = l & 15;
    const int rg = wv >> 1, bh = wv & 1;
    const int bfr = bh * 16 + lo;
    const int ue = tid >> 5, ub = tid & 31;

    __shared__ half_t s_hd[32 * 520];
    __shared__ float s_g[32][65];
    __shared__ float s_c[16][32];
    __shared__ float s_h[16][32];
    __shared__ half_t s_hh[16][32];
    __shared__ int s_len[32];

    if (tid < 32) s_len[tid] = lens[tid];
    s_c[ue][ub] = 0.f;
    s_h[ue][ub] = 0.f;

    const int pr = dir * 2048 + sub * 64 + rg * 16 + lo;
    const half_t* wih_b = wihp + (size_t)pr * 512;
    const half_t* whh_b = whhp + (size_t)pr * 512;
    const float bias_n = bsum[pr];

    // hoist recurrent weights into registers (constant across all 256 steps)
    h8 wihreg[16], whhreg[16];
#pragma unroll
    for (int ks = 0; ks < 16; ++ks) {
        wihreg[ks] = *(const h8*)(wih_b + ks * 32 + quad * 8);
        whhreg[ks] = *(const h8*)(whh_b + ks * 32 + quad * 8);
    }

    int sp = 0, sn = HOP;
    __syncthreads();

    for (int t = 0; t < 256; ++t) {
        // wait for all producers of slot sp (slot 0 pre-zeroed => skip)
        if (t > 0) {
            if (tid >= 64 && tid < 96) {
                const unsigned want = (unsigned)t;
                const unsigned* fp = mbE + (size_t)(dir * 32 + sub) * 64 + (tid - 64);
                while (__hip_atomic_load(fp, __ATOMIC_RELAXED, __HIP_MEMORY_SCOPE_AGENT) < want)
                    __builtin_amdgcn_s_sleep(1);
            }
            __syncthreads();
        }

        // issue h-slot coop loads (fresh cold addresses -> L3)
        const half_t* src = henc + (size_t)sp * 32768 + (size_t)dir * 16384;
        h8 tmp0 = *(const h8*)(src + (size_t)(tid + 0 * 512) * 8);
        h8 tmp1 = *(const h8*)(src + (size_t)(tid + 1 * 512) * 8);
        h8 tmp2 = *(const h8*)(src + (size_t)(tid + 2 * 512) * 8);
        h8 tmp3 = *(const h8*)(src + (size_t)(tid + 3 * 512) * 8);

        // x-part MFMA overlaps the h loads (a from global X, b from regs)
        const int lb = s_len[bfr];
        int tt = (dir == 0) ? t : (lb - 1 - t);
        tt = tt < 0 ? 0 : tt;
        const half_t* xr = X + ((size_t)bfr * 256 + tt) * 512;
        f4 accA = {0.f, 0.f, 0.f, 0.f}, accB = {0.f, 0.f, 0.f, 0.f};
#pragma unroll
        for (int ks = 0; ks < 16; ++ks) {
            h8 a = *(const h8*)(xr + ks * 32 + quad * 8);
            accA = __builtin_amdgcn_mfma_f32_16x16x32_f16(a, wihreg[ks], accA, 0, 0, 0);
        }

        // stage h into LDS
        {
            int c0 = tid;
            *(h8*)(s_hd + (size_t)(c0 >> 6) * 520 + (c0 & 63) * 8) = tmp0;
            int c1 = tid + 512;
            *(h8*)(s_hd + (size_t)(c1 >> 6) * 520 + (c1 & 63) * 8) = tmp1;
            int c2 = tid + 1024;
            *(h8*)(s_hd + (size_t)(c2 >> 6) * 520 + (c2 & 63) * 8) = tmp2;
            int c3 = tid + 1536;
            *(h8*)(s_hd + (size_t)(c3 >> 6) * 520 + (c3 & 63) * 8) = tmp3;
        }
        __syncthreads();

#pragma unroll
        for (int ks = 0; ks < 16; ++ks) {
            h8 a = *(const h8*)(s_hd + (size_t)bfr * 520 + ks * 32 + quad * 8);
            accB = __builtin_amdgcn_mfma_f32_16x16x32_f16(a, whhreg[ks], accB, 0, 0, 0);
        }
        const int bm = bh * 16 + quad * 4, cm = rg * 16 + lo;
#pragma unroll
        for (int r = 0; r < 4; ++r) s_g[bm + r][cm] = accA[r] + accB[r] + bias_n;
        __syncthreads();
        {
            float gi = s_g[ub][ue * 4 + 0], gf = s_g[ub][ue * 4 + 1];
            float gg = s_g[ub][ue * 4 + 2], go = s_g[ub][ue * 4 + 3];
            float cn = sigm(gf) * s_c[ue][ub] + sigm(gi) * tanh_f(gg);
            float hn = sigm(go) * tanh_f(cn);
            if (t < s_len[ub]) { s_c[ue][ub] = cn; s_h[ue][ub] = hn; }
            s_hh[ue][ub] = (half_t)s_h[ue][ub];
        }
        __syncthreads();
        if (tid < 64 && t < 255) {
            int b2 = tid >> 1, e8 = (tid & 1) * 8;
            union { half_t h[8]; u4 v; } pk;
#pragma unroll
            for (int i = 0; i < 8; ++i) pk.h[i] = s_hh[e8 + i][b2];
            st_wt128(henc + (size_t)sn * 32768 + (size_t)dir * 16384
                     + (size_t)b2 * 512 + sub * 16 + e8, pk.v);
            // ack own data stores, then fan out one flag per consumer
            asm volatile("s_waitcnt vmcnt(0)");
            if (tid < 32)
                __hip_atomic_store(mbE + ((size_t)(dir * 32 + tid) * 64 + sub),
                                   (unsigned)(t + 1), __ATOMIC_RELAXED,
                                   __HIP_MEMORY_SCOPE_AGENT);
        }
        if (t < 255) { sp = sn; sn += HOP; if (sn >= RING_E) sn -= RING_E; }
    }
    hd0[(size_t)ub * 1024 + dir * 512 + sub * 16 + ue] = (half_t)s_h[ue][ub];
    cel[(size_t)ub * 1024 + dir * 512 + sub * 16 + ue] = s_c[ue][ub];
}

// ---------------- persistent decoder LSTM + projection consumers ----------
// Grid 73 x 512 thr.
//   Blocks 0..63 (core): block j owns h-elems [16j,16j+16). Weff fragments
//     in VGPRs; h ring slots hop by HOP mod RING_D; slot 0 = encoder hid.
//     Store: wave 0, dwordx4; 1 flag/producer fanned to 73 consumers.
//     Poll: wave 1.
//   Blocks 64..72 (proj): lagging consumers; block 64+p computes mel rows
//     [16p,16p+16) (p<8) or gate (p==8) for pos t-1 from h_t. Never gate
//     producers.
__global__ __launch_bounds__(512) void k_dec(const half_t* __restrict__ Weff,
                                             const half_t* __restrict__ W0,
                                             const float* __restrict__ beff,
                                             const float* __restrict__ b0,
                                             const half_t* __restrict__ projwb,
                                             const half_t* __restrict__ projg,
                                             const float* __restrict__ projb,
                                             const float* __restrict__ gateb,
                                             const int* __restrict__ mlens,
                                             const float* __restrict__ cel,
                                             half_t* __restrict__ hd,   // ring [RING_D][32][1024]
                                             float* __restrict__ out,
                                             unsigned* __restrict__ mbD) { // [73 consumers][64]
    const int j = blockIdx.x;
    const int tid = threadIdx.x;
    const int wv = tid >> 6, l = tid & 63, quad = l >> 4, lo = l & 15;

    __shared__ half_t s_hd[32 * 1032];
    __shared__ float s_g[32][65];
    __shared__ float s_c[16][32];
    __shared__ half_t s_hh[16][32];
    __shared__ int s_len[32];

    if (j < 64) {
        // ---------------- core recurrence block ----------------
        const int rg = wv >> 1, bh = wv & 1;
        const int bfr = bh * 16 + lo;
        const int ue = tid >> 5, ub = tid & 31;

        s_c[ue][ub] = cel[(size_t)ub * 1024 + j * 16 + ue];
        const int pr = j * 64 + rg * 16 + lo;
        const float biasE = beff[pr], bias0 = b0[pr];
        const half_t* wbE = Weff + (size_t)pr * 1024;
        const half_t* wb0 = W0 + (size_t)pr * 1024;

        // hoist steady-state recurrent weights into registers
        h8 wreg[32];
#pragma unroll
        for (int ks = 0; ks < 32; ++ks)
            wreg[ks] = *(const h8*)(wbE + ks * 32 + quad * 8);

        int sp = 0, sn = HOP;
        __syncthreads();

        for (int t = 1; t <= TMEL; ++t) {
            // wait for all producers of slot sp (t==1: slot 0 from k_enc,
            // visible via kernel-boundary coherence => skip)
            if (t > 1) {
                if (tid >= 64 && tid < 128) {
                    const unsigned want = (unsigned)(t - 1);
                    const unsigned* fp = mbD + (size_t)j * 64 + (tid - 64);
                    while (__hip_atomic_load(fp, __ATOMIC_RELAXED, __HIP_MEMORY_SCOPE_AGENT) < want)
                        __builtin_amdgcn_s_sleep(1);
                }
                __syncthreads();
            }

            // cooperative load of h slot (fresh cold addresses)
            const half_t* src = hd + (size_t)sp * 32768;
            {
                h8 tp[8];
#pragma unroll
                for (int i = 0; i < 8; ++i)
                    tp[i] = *(const h8*)(src + (size_t)(tid + i * 512) * 8);
#pragma unroll
                for (int i = 0; i < 8; ++i) {
                    int c = tid + i * 512;
                    *(h8*)(s_hd + (size_t)(c >> 7) * 1032 + (c & 127) * 8) = tp[i];
                }
            }
            __syncthreads();

            const half_t* ar = s_hd + (size_t)bfr * 1032 + quad * 8;
            f4 acc = {0.f, 0.f, 0.f, 0.f}, acc2 = {0.f, 0.f, 0.f, 0.f};
            if (t == 1) {
#pragma unroll 8
                for (int ks = 0; ks < 32; ks += 2) {
                    h8 a0 = *(const h8*)(ar + ks * 32);
                    h8 a1 = *(const h8*)(ar + ks * 32 + 32);
                    acc = __builtin_amdgcn_mfma_f32_16x16x32_f16(a0, *(const h8*)(wb0 + ks * 32 + quad * 8), acc, 0, 0, 0);
                    acc2 = __builtin_amdgcn_mfma_f32_16x16x32_f16(a1, *(const h8*)(wb0 + ks * 32 + 32 + quad * 8), acc2, 0, 0, 0);
                }
            } else {
#pragma unroll
                for (int ks = 0; ks < 32; ks += 2) {
                    h8 a0 = *(const h8*)(ar + ks * 32);
                    h8 a1 = *(const h8*)(ar + ks * 32 + 32);
                    acc = __builtin_amdgcn_mfma_f32_16x16x32_f16(a0, wreg[ks], acc, 0, 0, 0);
                    acc2 = __builtin_amdgcn_mfma_f32_16x16x32_f16(a1, wreg[ks + 1], acc2, 0, 0, 0);
                }
            }
            const float bn = (t == 1) ? bias0 : biasE;
            const int bm = bh * 16 + quad * 4, cm = rg * 16 + lo;
#pragma unroll
            for (int r = 0; r < 4; ++r) s_g[bm + r][cm] = acc[r] + acc2[r] + bn;
            __syncthreads();
            {
                float gi = s_g[ub][ue * 4 + 0], gf = s_g[ub][ue * 4 + 1];
                float gg = s_g[ub][ue * 4 + 2], go = s_g[ub][ue * 4 + 3];
                float cn = sigm(gf) * s_c[ue][ub] + sigm(gi) * tanh_f(gg);
                s_c[ue][ub] = cn;
                s_hh[ue][ub] = (half_t)(sigm(go) * tanh_f(cn));
            }
            __syncthreads();
            if (tid < 64) {
                int b2 = tid >> 1, e8 = (tid & 1) * 8;
                union { half_t h[8]; u4 v; } pk;
#pragma unroll
                for (int i = 0; i < 8; ++i) pk.h[i] = s_hh[e8 + i][b2];
                st_wt128(hd + (size_t)sn * 32768 + (size_t)b2 * 1024 + j * 16 + e8, pk.v);
                // ack own data stores, then fan out one flag per consumer
                asm volatile("s_waitcnt vmcnt(0)");
                __hip_atomic_store(mbD + ((size_t)tid * 64 + j), (unsigned)t,
                                   __ATOMIC_RELAXED, __HIP_MEMORY_SCOPE_AGENT);
                if (tid < 9)
                    __hip_atomic_store(mbD + ((size_t)(64 + tid) * 64 + j), (unsigned)t,
                                       __ATOMIC_RELAXED, __HIP_MEMORY_SCOPE_AGENT);
            }
            sp = sn; sn += HOP; if (sn >= RING_D) sn -= RING_D;
        }
    } else {
        // ---------------- lagging projection consumer block ----------------
        const int pj = j - 64;
        const bool meld = (pj < 8);
        const bool duty = (wv < 2);
        const int bh2 = wv & 1;
        const half_t* pw = meld ? (projwb + (size_t)(pj * 16 + lo) * 1024)
                                : (projg + (size_t)lo * 1024);
        const float biasP = meld ? projb[pj * 16 + lo] : gateb[0];

        h8 pwreg[32];
        if (duty) {
#pragma unroll
            for (int ks = 0; ks < 32; ++ks)
                pwreg[ks] = *(const h8*)(pw + ks * 32 + quad * 8);
        }
        if (tid < 32) s_len[tid] = mlens[tid];

        int spP = HOP;
        __syncthreads();

        for (int t = 1; t <= TMEL; ++t) {
            // wait for all producers of slot spP (contains h_t)
            if (tid < 64) {
                const unsigned want = (unsigned)t;
                const unsigned* fp = mbD + (size_t)(64 + pj) * 64 + tid;
                while (__hip_atomic_load(fp, __ATOMIC_RELAXED, __HIP_MEMORY_SCOPE_AGENT) < want)
                    __builtin_amdgcn_s_sleep(1);
            }
            __syncthreads();

            // cooperative load of h_t slot
            const half_t* src = hd + (size_t)spP * 32768;
            {
                h8 tp[8];
#pragma unroll
                for (int i = 0; i < 8; ++i)
                    tp[i] = *(const h8*)(src + (size_t)(tid + i * 512) * 8);
#pragma unroll
                for (int i = 0; i < 8; ++i) {
                    int c = tid + i * 512;
                    *(h8*)(s_hd + (size_t)(c >> 7) * 1032 + (c & 127) * 8) = tp[i];
                }
            }
            __syncthreads();

            if (duty) {
                const half_t* ar = s_hd + (size_t)(bh2 * 16 + lo) * 1032 + quad * 8;
                f4 accm = {0.f, 0.f, 0.f, 0.f}, accm2 = {0.f, 0.f, 0.f, 0.f};
#pragma unroll
                for (int ks = 0; ks < 32; ks += 2) {
                    h8 a0 = *(const h8*)(ar + ks * 32);
                    h8 a1 = *(const h8*)(ar + ks * 32 + 32);
                    accm = __builtin_amdgcn_mfma_f32_16x16x32_f16(a0, pwreg[ks], accm, 0, 0, 0);
                    accm2 = __builtin_amdgcn_mfma_f32_16x16x32_f16(a1, pwreg[ks + 1], accm2, 0, 0, 0);
                }
                accm[0] += accm2[0]; accm[1] += accm2[1];
                accm[2] += accm2[2]; accm[3] += accm2[3];
                const int pos = t - 1;
                if (meld) {
#pragma unroll
                    for (int r = 0; r < 4; ++r) {
                        int b = bh2 * 16 + quad * 4 + r;
                        float v = accm[r] + biasP;
                        if (pos > s_len[b]) v = 0.f;
                        __builtin_nontemporal_store(v,
                            &out[(size_t)b * (TMEL * MM) + (size_t)pos * MM + pj * 16 + lo]);
                    }
                } else if (lo == 0) {
#pragma unroll
                    for (int r = 0; r < 4; ++r) {
                        int b = bh2 * 16 + quad * 4 + r;
                        float v = accm[r] + biasP;
                        if (pos > s_len[b]) v = 1000.f;
                        __builtin_nontemporal_store(v, &out[GATE_OFF + (size_t)b * TMEL + pos]);
                    }
                }
            }
            __syncthreads();   // protect s_hd before next stage
            spP += HOP; if (spP >= RING_D) spP -= RING_D;
        }
    }
}

// ---------------------------------------------------------------------------

extern "C" void kernel_launch(void* const* d_in, const int* in_sizes, int n_in,
                              void* d_out, int out_size, void* d_ws, size_t ws_size,
                              hipStream_t stream) {
    const int* x = (const int*)d_in[0];
    const int* tlens = (const int*)d_in[1];
    const int* mlens = (const int*)d_in[3];
    const float* emb = (const float*)d_in[4];
    const float* c1w = (const float*)d_in[5];
    const float* c1b = (const float*)d_in[6];
    const float* bn1g = (const float*)d_in[7];
    const float* bn1b = (const float*)d_in[8];
    const float* c2w = (const float*)d_in[9];
    const float* c2b = (const float*)d_in[10];
    const float* bn2g = (const float*)d_in[11];
    const float* bn2b = (const float*)d_in[12];
    const float* wihf = (const float*)d_in[13];
    const float* whhf = (const float*)d_in[14];
    const float* bihf = (const float*)d_in[15];
    const float* bhhf = (const float*)d_in[16];
    const float* wihb = (const float*)d_in[17];
    const float* whhb = (const float*)d_in[18];
    const float* bihb = (const float*)d_in[19];
    const float* bhhb = (const float*)d_in[20];
    const float* dwih = (const float*)d_in[21];
    const float* dwhh = (const float*)d_in[22];
    const float* dbih = (const float*)d_in[23];
    const float* dbhh = (const float*)d_in[24];
    const float* projw = (const float*)d_in[25];
    const float* projb = (const float*)d_in[26];
    const float* gatew = (const float*)d_in[27];
    const float* gateb = (const float*)d_in[28];
    float* out = (float*)d_out;
    char* ws = (char*)d_ws;

    unsigned* mbE = (unsigned*)(ws + WS_MBE);
    unsigned* mbD = (unsigned*)(ws + WS_MBD);
    half_t* henc = (half_t*)(ws + WS_HENC);
    half_t* hd = (half_t*)(ws + WS_HD);
    half_t* bufX = (half_t*)(ws + WS_BUFX);
    half_t* bufY = (half_t*)(ws + WS_BUFY);
    float* convf = (float*)(ws + WS_CONVF);
    half_t* weff = (half_t*)(ws + WS_WEFF);
    half_t* w0 = (half_t*)(ws + WS_W0);
    half_t* wp1 = (half_t*)(ws + WS_WP1);
    half_t* wp2 = (half_t*)(ws + WS_WP2);
    float* meanb = (float*)(ws + WS_MEAN);
    float* rstdb = (float*)(ws + WS_RSTD);
    half_t* wihp = (half_t*)(ws + WS_WIHP);
    half_t* whhp = (half_t*)(ws + WS_WHHP);
    float* bsum = (float*)(ws + WS_BSUM);
    float* beff = (float*)(ws + WS_BEFF);
    float* b0 = (float*)(ws + WS_B0);
    half_t* projwb = (half_t*)(ws + WS_PROJW);
    half_t* projg = (half_t*)(ws + WS_PROJG);
    float* cel = (float*)(ws + WS_CEL);

    // zero mailboxes + encoder ring slot 0 (re-done every launch/replay)
    hipMemsetAsync(d_ws, 0, (size_t)WS_ZERO_BYTES, stream);

    // front-end
    k_embed<<<NROWS, 256, 0, stream>>>(x, emb, bufX);
    k_packconvw<<<(3 * EE * EE + 255) / 256, 256, 0, stream>>>(c1w, wp1);
    k_conv<<<dim3(128, 32), 256, 0, stream>>>(bufX, wp1, c1b, convf);
    k_bnstats<<<EE, 256, 0, stream>>>(convf, meanb, rstdb);
    k_bnapply<<<(NROWS * EE) / 256, 256, 0, stream>>>(convf, meanb, rstdb, bn1g, bn1b, bufY);
    k_packconvw<<<(3 * EE * EE + 255) / 256, 256, 0, stream>>>(c2w, wp2);
    k_conv<<<dim3(128, 32), 256, 0, stream>>>(bufY, wp2, c2b, convf);
    k_bnstats<<<EE, 256, 0, stream>>>(convf, meanb, rstdb);
    k_bnapply<<<(NROWS * EE) / 256, 256, 0, stream>>>(convf, meanb, rstdb, bn2g, bn2b, bufX);

    // encoder weight prep
    const int encTot = 2048 * 512;
    k_packrec<<<(encTot + 255) / 256, 256, 0, stream>>>(wihf, wihp, HH, 9, encTot);
    k_packrec<<<(encTot + 255) / 256, 256, 0, stream>>>(wihb, wihp + encTot, HH, 9, encTot);
    k_packrec<<<(encTot + 255) / 256, 256, 0, stream>>>(whhf, whhp, HH, 9, encTot);
    k_packrec<<<(encTot + 255) / 256, 256, 0, stream>>>(whhb, whhp + encTot, HH, 9, encTot);
    k_bsumenc<<<16, 256, 0, stream>>>(bihf, bhhf, bihb, bhhb, bsum);

    // persistent bidirectional encoder (writes hd ring slot 0 + cel)
    k_enc<<<64, 512, 0, stream>>>(bufX, wihp, whhp, bsum, tlens, henc, hd, cel, mbE);

    // decoder weight prep (into retired convf region)
    k_weff<<<dim3(4096, 4), 256, 0, stream>>>(dwhh, dwih, projw, weff, w0);
    k_bdec<<<16, 256, 0, stream>>>(dbih, dbhh, dwih, projb, beff, b0);
    k_cast<<<(MM * DD + 255) / 256, 256, 0, stream>>>(projw, projwb, MM * DD);
    k_projg<<<(16 * DD + 255) / 256, 256, 0, stream>>>(gatew, projg);

    // persistent decoder (64 core + 9 projection blocks)
    k_dec<<<73, 512, 0, stream>>>(weff, w0, beff, b0, projwb, projg, projb, gateb,
                                  mlens, cel, hd, out, mbD);

    // mask output
    k_mask<<<(B_ * TMEL + 255) / 256, 256, 0, stream>>>(mlens, out);

    (void)in_sizes; (void)n_in; (void)out_size; (void)ws_size;
}

// Round 4
// 4901.045 us; speedup vs baseline: 3.3261x; 1.0507x over previous
//
#include <hip/hip_runtime.h>

// ---------------------------------------------------------------------------
// TTS forward on MI355X.
//   embed -> conv1(+BN+ReLU) -> conv2(+BN+ReLU) -> persistent biLSTM encoder
//   -> W_eff fold (decoder input GEMM folded into recurrent weights)
//   -> persistent 800-step decoder LSTM + lagging projection consumer blocks
// Round 7: L3-resident exchange. h-ring data stores and flag stores are
// return-less global atomics (execute at the coherence point AND leave the
// line resident in L3), so consumer cache misses are served by L3 instead
// of HBM. vmcnt(0) on the atomic is a true global-visibility ack. All
// structure (ring, mailboxes, wave roles, math) identical to round 6.
// ---------------------------------------------------------------------------

typedef float f4 __attribute__((ext_vector_type(4)));
typedef _Float16 h8 __attribute__((ext_vector_type(8)));
typedef _Float16 half_t;
typedef unsigned long long u64;

#define B_    32
#define LTXT  256
#define TMEL  800
#define EE    512
#define HH    512
#define DD    1024
#define MM    128
#define NROWS 8192          // B_*LTXT
#define GATE_OFF 3276800    // B_*TMEL*MM
#define MASK_OFF 3302400    // + B_*TMEL

#define RING_D 801          // decoder h ring slots (never reused in 800 steps)
#define RING_E 257          // encoder h ring slots
#define HOP    13           // slot hop stride (coprime with both rings)

// workspace offsets (bytes)
#define WS_MBE        0ull             // enc mailboxes: 64 consumers x 64 u32 = 16 KiB
#define WS_MBD        16384ull         // dec mailboxes: 73 consumers x 64 u32 (pad 32 KiB)
#define WS_HENC       49152ull         // RING_E * 65536
#define WS_ZERO_BYTES 81920ull         // mailboxes + henc slot 0
#define WS_HD         16891904ull      // RING_D * 65536
#define WS_BUFX       69386240ull      // 8 MiB
#define WS_BUFY       77774848ull      // 8 MiB
#define WS_CONVF      86163456ull      // 16 MiB (reused by WEFF/W0 after convs)
#define WS_WEFF       86163456ull
#define WS_W0         94552064ull
#define WS_WP1        102940672ull
#define WS_WP2        104513536ull
#define WS_WIHP       106086400ull     // 4 MiB
#define WS_WHHP       110280704ull     // 4 MiB
#define WS_BSUM       114475008ull
#define WS_BEFF       114491392ull
#define WS_B0         114507776ull
#define WS_MEAN       114524160ull
#define WS_RSTD       114526208ull
#define WS_PROJW      114528256ull
#define WS_PROJG      114790400ull
#define WS_CEL        114823168ull
// total ~114.95 MB

__device__ __forceinline__ float sigm(float x) { return 1.f / (1.f + __expf(-x)); }
__device__ __forceinline__ float tanh_f(float x) {
    float e = __expf(2.f * x);
    return 1.f - 2.f / (e + 1.f);
}

// return-less atomic swap: executes at coherence point, line stays L3-resident
__device__ __forceinline__ void st_atom64(void* p, u64 v) {
    asm volatile("global_atomic_swap_x2 %0, %1, off" :: "v"(p), "v"(v) : "memory");
}
__device__ __forceinline__ void st_atom32(unsigned* p, unsigned v) {
    asm volatile("global_atomic_swap %0, %1, off" :: "v"(p), "v"(v) : "memory");
}

// ---------------- small prep kernels ----------------

__global__ void k_embed(const int* __restrict__ x, const float* __restrict__ emb,
                        half_t* __restrict__ out) {
    int row = blockIdx.x;
    int tok = x[row];
    const float* e = emb + (size_t)tok * EE;
    half_t* o = out + (size_t)row * EE;
    for (int c = threadIdx.x; c < EE; c += blockDim.x) o[c] = (half_t)e[c];
}

__global__ void k_packconvw(const float* __restrict__ w, half_t* __restrict__ wp) {
    int idx = blockIdx.x * 256 + threadIdx.x;
    if (idx >= 3 * EE * EE) return;
    int s = idx / (EE * EE);
    int rem = idx - s * EE * EE;
    int eo = rem >> 9, ei = rem & 511;
    wp[idx] = (half_t)w[(size_t)eo * (EE * 3) + ei * 3 + s];
}

__global__ __launch_bounds__(256) void k_conv(const half_t* __restrict__ A,
                                              const half_t* __restrict__ Wp,
                                              const float* __restrict__ bias,
                                              float* __restrict__ out) {
    const int nt = blockIdx.x, et = blockIdx.y;
    const int tid = threadIdx.x;
    const int wv = tid >> 6, l = tid & 63, quad = l >> 4, lo = l & 15;
    const int rowA = nt * 64 + wv * 16 + lo;
    const int eo = et * 16 + lo;
    f4 acc = {0.f, 0.f, 0.f, 0.f};
    for (int s = 0; s < 3; ++s) {
        int lsp = (rowA & 255) + s - 1;
        bool valid = (lsp >= 0) && (lsp < 256);
        int rs = rowA + s - 1;
        rs = rs < 0 ? 0 : (rs > NROWS - 1 ? NROWS - 1 : rs);
        const half_t* ab = A + (size_t)rs * EE;
        const half_t* wb = Wp + ((size_t)s * EE + eo) * EE;
#pragma unroll 4
        for (int ks = 0; ks < 16; ++ks) {
            h8 a = {0, 0, 0, 0, 0, 0, 0, 0};
            if (valid) a = *(const h8*)(ab + ks * 32 + quad * 8);
            h8 b = *(const h8*)(wb + ks * 32 + quad * 8);
            acc = __builtin_amdgcn_mfma_f32_16x16x32_f16(a, b, acc, 0, 0, 0);
        }
    }
    const int orow = nt * 64 + wv * 16 + quad * 4;
    const float bv = bias[eo];
#pragma unroll
    for (int r = 0; r < 4; ++r) out[(size_t)(orow + r) * EE + eo] = acc[r] + bv;
}

__global__ __launch_bounds__(256) void k_bnstats(const float* __restrict__ x,
                                                 float* __restrict__ mean,
                                                 float* __restrict__ rstd) {
    const int c = blockIdx.x;
    float s = 0.f, ss = 0.f;
    for (int n = threadIdx.x; n < NROWS; n += 256) {
        float v = x[(size_t)n * EE + c];
        s += v; ss += v * v;
    }
#pragma unroll
    for (int off = 32; off > 0; off >>= 1) { s += __shfl_down(s, off); ss += __shfl_down(ss, off); }
    __shared__ float as[4], ass[4];
    int wv = threadIdx.x >> 6;
    if ((threadIdx.x & 63) == 0) { as[wv] = s; ass[wv] = ss; }
    __syncthreads();
    if (threadIdx.x == 0) {
        float S = as[0] + as[1] + as[2] + as[3];
        float SS = ass[0] + ass[1] + ass[2] + ass[3];
        float m = S / (float)NROWS;
        float var = SS / (float)NROWS - m * m;
        mean[c] = m;
        rstd[c] = rsqrtf(var + 1e-5f);
    }
}

__global__ void k_bnapply(const float* __restrict__ x, const float* __restrict__ mean,
                          const float* __restrict__ rstd, const float* __restrict__ g,
                          const float* __restrict__ beta, half_t* __restrict__ out) {
    int idx = blockIdx.x * 256 + threadIdx.x;
    if (idx >= NROWS * EE) return;
    int c = idx & (EE - 1);
    float v = (x[idx] - mean[c]) * rstd[c] * g[c] + beta[c];
    out[idx] = (half_t)(v > 0.f ? v : 0.f);
}

__global__ void k_packrec(const float* __restrict__ src, half_t* __restrict__ dst,
                          int Hdim, int kshift, int total) {
    int idx = blockIdx.x * 256 + threadIdx.x;
    if (idx >= total) return;
    int p = idx >> kshift;
    int k = idx & ((1 << kshift) - 1);
    int he = p >> 2, g = p & 3;
    dst[idx] = (half_t)src[((size_t)g * Hdim + he) * (size_t)(1 << kshift) + k];
}

__global__ void k_bsumenc(const float* __restrict__ bf, const float* __restrict__ bhf,
                          const float* __restrict__ bb, const float* __restrict__ bhb,
                          float* __restrict__ bsum) {
    int p = blockIdx.x * 256 + threadIdx.x;
    if (p >= 4096) return;
    int dir = p >> 11, pp = p & 2047;
    int he = pp >> 2, g = pp & 3;
    int row = g * HH + he;
    bsum[p] = dir ? (bb[row] + bhb[row]) : (bf[row] + bhf[row]);
}

__global__ __launch_bounds__(256) void k_weff(const float* __restrict__ dwhh,
                                              const float* __restrict__ dwih,
                                              const float* __restrict__ projw,
                                              half_t* __restrict__ weff,
                                              half_t* __restrict__ w0) {
    int row = blockIdx.x;
    int k = blockIdx.y * 256 + threadIdx.x;
    float v = dwhh[(size_t)row * DD + k];
    float acc = v;
    for (int m = 0; m < MM; ++m) acc += dwih[(size_t)row * MM + m] * projw[(size_t)m * DD + k];
    int p = ((row & (DD - 1)) << 2) | (row >> 10);
    weff[(size_t)p * DD + k] = (half_t)acc;
    w0[(size_t)p * DD + k] = (half_t)v;
}

__global__ void k_bdec(const float* __restrict__ dbih, const float* __restrict__ dbhh,
                       const float* __restrict__ dwih, const float* __restrict__ projb,
                       float* __restrict__ beff, float* __restrict__ b0) {
    int p = blockIdx.x * 256 + threadIdx.x;
    if (p >= 4096) return;
    int he = p >> 2, g = p & 3;
    int row = g * DD + he;
    float bb = dbih[row] + dbhh[row];
    float acc = bb;
    for (int m = 0; m < MM; ++m) acc += dwih[(size_t)row * MM + m] * projb[m];
    b0[p] = bb;
    beff[p] = acc;
}

__global__ void k_cast(const float* __restrict__ src, half_t* __restrict__ dst, int n) {
    int idx = blockIdx.x * 256 + threadIdx.x;
    if (idx < n) dst[idx] = (half_t)src[idx];
}

__global__ void k_projg(const float* __restrict__ gw, half_t* __restrict__ pg) {
    int idx = blockIdx.x * 256 + threadIdx.x;
    if (idx >= 16 * DD) return;
    int row = idx >> 10, k = idx & (DD - 1);
    pg[idx] = (half_t)(row == 0 ? gw[k] : 0.f);
}

__global__ void k_mask(const int* __restrict__ lens, float* __restrict__ out) {
    int idx = blockIdx.x * 256 + threadIdx.x;
    if (idx >= B_ * TMEL) return;
    int b = idx / TMEL, t = idx - b * TMEL;
    out[MASK_OFF + idx] = (t > lens[b]) ? 1.f : 0.f;
}

// ---------------- persistent bidirectional encoder LSTM ----------------
// 64 blocks x 512 thr. dir=j>>5, sub=j&31 owns 16 h-elems. Recurrent weights
// in VGPRs. Store: wave 0, two 8B atomic swaps/lane (L3-resident), vmcnt(0)
// ack, then lanes<32 fan one flag atomic out to same-dir consumers.
// Poll: wave 1 lanes<32 poll own private mailbox.
__global__ __launch_bounds__(512) void k_enc(const half_t* __restrict__ X,
                                             const half_t* __restrict__ wihp,
                                             const half_t* __restrict__ whhp,
                                             const float* __restrict__ bsum,
                                             const int* __restrict__ lens,
                                             half_t* __restrict__ henc,   // ring [RING_E][2][32][512]
                                             half_t* __restrict__ hd0,    // dec ring slot 0: [32][1024]
                                             float* __restrict__ cel,     // [32][1024]
                                             unsigned* __restrict__ mbE) { // [64 consumers][64]
    const int j = blockIdx.x;
    const int dir = j >> 5, sub = j & 31;
    const int tid = threadIdx.x;
    const int wv = tid >> 6, l = tid & 63, quad = l >> 4, lo = l & 15;
    const int rg = wv >> 1, bh = wv & 1;
    const int bfr = bh * 16 + lo;
    const int ue = tid >> 5, ub = tid & 31;

    __shared__ half_t s_hd[32 * 520];
    __shared__ float s_g[32][65];
    __shared__ float s_c[16][32];
    __shared__ float s_h[16][32];
    __shared__ half_t s_hh[16][32];
    __shared__ int s_len[32];

    if (tid < 32) s_len[tid] = lens[tid];
    s_c[ue][ub] = 0.f;
    s_h[ue][ub] = 0.f;

    const int pr = dir * 2048 + sub * 64 + rg * 16 + lo;
    const half_t* wih_b = wihp + (size_t)pr * 512;
    const half_t* whh_b = whhp + (size_t)pr * 512;
    const float bias_n = bsum[pr];

    // hoist recurrent weights into registers (constant across all 256 steps)
    h8 wihreg[16], whhreg[16];
#pragma unroll
    for (int ks = 0; ks < 16; ++ks) {
        wihreg[ks] = *(const h8*)(wih_b + ks * 32 + quad * 8);
        whhreg[ks] = *(const h8*)(whh_b + ks * 32 + quad * 8);
    }

    int sp = 0, sn = HOP;
    __syncthreads();

    for (int t = 0; t < 256; ++t) {
        // wait for all producers of slot sp (slot 0 pre-zeroed => skip)
        if (t > 0) {
            if (tid >= 64 && tid < 96) {
                const unsigned want = (unsigned)t;
                const unsigned* fp = mbE + (size_t)(dir * 32 + sub) * 64 + (tid - 64);
                while (__hip_atomic_load(fp, __ATOMIC_RELAXED, __HIP_MEMORY_SCOPE_AGENT) < want)
                    __builtin_amdgcn_s_sleep(1);
            }
            __syncthreads();
        }

        // issue h-slot coop loads (never-reused addresses, L3-resident)
        const half_t* src = henc + (size_t)sp * 32768 + (size_t)dir * 16384;
        h8 tmp0 = *(const h8*)(src + (size_t)(tid + 0 * 512) * 8);
        h8 tmp1 = *(const h8*)(src + (size_t)(tid + 1 * 512) * 8);
        h8 tmp2 = *(const h8*)(src + (size_t)(tid + 2 * 512) * 8);
        h8 tmp3 = *(const h8*)(src + (size_t)(tid + 3 * 512) * 8);

        // x-part MFMA overlaps the h loads (a from global X, b from regs)
        const int lb = s_len[bfr];
        int tt = (dir == 0) ? t : (lb - 1 - t);
        tt = tt < 0 ? 0 : tt;
        const half_t* xr = X + ((size_t)bfr * 256 + tt) * 512;
        f4 accA = {0.f, 0.f, 0.f, 0.f}, accB = {0.f, 0.f, 0.f, 0.f};
#pragma unroll
        for (int ks = 0; ks < 16; ++ks) {
            h8 a = *(const h8*)(xr + ks * 32 + quad * 8);
            accA = __builtin_amdgcn_mfma_f32_16x16x32_f16(a, wihreg[ks], accA, 0, 0, 0);
        }

        // stage h into LDS
        {
            int c0 = tid;
            *(h8*)(s_hd + (size_t)(c0 >> 6) * 520 + (c0 & 63) * 8) = tmp0;
            int c1 = tid + 512;
            *(h8*)(s_hd + (size_t)(c1 >> 6) * 520 + (c1 & 63) * 8) = tmp1;
            int c2 = tid + 1024;
            *(h8*)(s_hd + (size_t)(c2 >> 6) * 520 + (c2 & 63) * 8) = tmp2;
            int c3 = tid + 1536;
            *(h8*)(s_hd + (size_t)(c3 >> 6) * 520 + (c3 & 63) * 8) = tmp3;
        }
        __syncthreads();

#pragma unroll
        for (int ks = 0; ks < 16; ++ks) {
            h8 a = *(const h8*)(s_hd + (size_t)bfr * 520 + ks * 32 + quad * 8);
            accB = __builtin_amdgcn_mfma_f32_16x16x32_f16(a, whhreg[ks], accB, 0, 0, 0);
        }
        const int bm = bh * 16 + quad * 4, cm = rg * 16 + lo;
#pragma unroll
        for (int r = 0; r < 4; ++r) s_g[bm + r][cm] = accA[r] + accB[r] + bias_n;
        __syncthreads();
        {
            float gi = s_g[ub][ue * 4 + 0], gf = s_g[ub][ue * 4 + 1];
            float gg = s_g[ub][ue * 4 + 2], go = s_g[ub][ue * 4 + 3];
            float cn = sigm(gf) * s_c[ue][ub] + sigm(gi) * tanh_f(gg);
            float hn = sigm(go) * tanh_f(cn);
            if (t < s_len[ub]) { s_c[ue][ub] = cn; s_h[ue][ub] = hn; }
            s_hh[ue][ub] = (half_t)s_h[ue][ub];
        }
        __syncthreads();
        if (tid < 64 && t < 255) {
            int b2 = tid >> 1, e8 = (tid & 1) * 8;
            union { half_t h[8]; u64 u[2]; } pk;
#pragma unroll
            for (int i = 0; i < 8; ++i) pk.h[i] = s_hh[e8 + i][b2];
            half_t* dst = henc + (size_t)sn * 32768 + (size_t)dir * 16384
                          + (size_t)b2 * 512 + sub * 16 + e8;
            st_atom64(dst, pk.u[0]);
            st_atom64(dst + 4, pk.u[1]);
            // ack own data atomics (true global visibility), then fan out flags
            asm volatile("s_waitcnt vmcnt(0)");
            if (tid < 32)
                st_atom32(mbE + ((size_t)(dir * 32 + tid) * 64 + sub), (unsigned)(t + 1));
        }
        if (t < 255) { sp = sn; sn += HOP; if (sn >= RING_E) sn -= RING_E; }
    }
    hd0[(size_t)ub * 1024 + dir * 512 + sub * 16 + ue] = (half_t)s_h[ue][ub];
    cel[(size_t)ub * 1024 + dir * 512 + sub * 16 + ue] = s_c[ue][ub];
}

// ---------------- persistent decoder LSTM + projection consumers ----------
// Grid 73 x 512 thr.
//   Blocks 0..63 (core): block j owns h-elems [16j,16j+16). Weff fragments
//     in VGPRs; h ring slots hop by HOP mod RING_D; slot 0 = encoder hid.
//     Store: wave 0, two 8B atomic swaps/lane; 1 flag/producer fanned to 73
//     consumers. Poll: wave 1.
//   Blocks 64..72 (proj): lagging consumers; block 64+p computes mel rows
//     [16p,16p+16) (p<8) or gate (p==8) for pos t-1 from h_t.
__global__ __launch_bounds__(512) void k_dec(const half_t* __restrict__ Weff,
                                             const half_t* __restrict__ W0,
                                             const float* __restrict__ beff,
                                             const float* __restrict__ b0,
                                             const half_t* __restrict__ projwb,
                                             const half_t* __restrict__ projg,
                                             const float* __restrict__ projb,
                                             const float* __restrict__ gateb,
                                             const int* __restrict__ mlens,
                                             const float* __restrict__ cel,
                                             half_t* __restrict__ hd,   // ring [RING_D][32][1024]
                                             float* __restrict__ out,
                                             unsigned* __restrict__ mbD) { // [73 consumers][64]
    const int j = blockIdx.x;
    const int tid = threadIdx.x;
    const int wv = tid >> 6, l = tid & 63, quad = l >> 4, lo = l & 15;

    __shared__ half_t s_hd[32 * 1032];
    __shared__ float s_g[32][65];
    __shared__ float s_c[16][32];
    __shared__ half_t s_hh[16][32];
    __shared__ int s_len[32];

    if (j < 64) {
        // ---------------- core recurrence block ----------------
        const int rg = wv >> 1, bh = wv & 1;
        const int bfr = bh * 16 + lo;
        const int ue = tid >> 5, ub = tid & 31;

        s_c[ue][ub] = cel[(size_t)ub * 1024 + j * 16 + ue];
        const int pr = j * 64 + rg * 16 + lo;
        const float biasE = beff[pr], bias0 = b0[pr];
        const half_t* wbE = Weff + (size_t)pr * 1024;
        const half_t* wb0 = W0 + (size_t)pr * 1024;

        // hoist steady-state recurrent weights into registers
        h8 wreg[32];
#pragma unroll
        for (int ks = 0; ks < 32; ++ks)
            wreg[ks] = *(const h8*)(wbE + ks * 32 + quad * 8);

        int sp = 0, sn = HOP;
        __syncthreads();

        for (int t = 1; t <= TMEL; ++t) {
            // wait for all producers of slot sp (t==1: slot 0 from k_enc,
            // visible via kernel-boundary coherence => skip)
            if (t > 1) {
                if (tid >= 64 && tid < 128) {
                    const unsigned want = (unsigned)(t - 1);
                    const unsigned* fp = mbD + (size_t)j * 64 + (tid - 64);
                    while (__hip_atomic_load(fp, __ATOMIC_RELAXED, __HIP_MEMORY_SCOPE_AGENT) < want)
                        __builtin_amdgcn_s_sleep(1);
                }
                __syncthreads();
            }

            // cooperative load of h slot (never-reused addresses, L3-resident)
            const half_t* src = hd + (size_t)sp * 32768;
            {
                h8 tp[8];
#pragma unroll
                for (int i = 0; i < 8; ++i)
                    tp[i] = *(const h8*)(src + (size_t)(tid + i * 512) * 8);
#pragma unroll
                for (int i = 0; i < 8; ++i) {
                    int c = tid + i * 512;
                    *(h8*)(s_hd + (size_t)(c >> 7) * 1032 + (c & 127) * 8) = tp[i];
                }
            }
            __syncthreads();

            const half_t* ar = s_hd + (size_t)bfr * 1032 + quad * 8;
            f4 acc = {0.f, 0.f, 0.f, 0.f}, acc2 = {0.f, 0.f, 0.f, 0.f};
            if (t == 1) {
#pragma unroll 8
                for (int ks = 0; ks < 32; ks += 2) {
                    h8 a0 = *(const h8*)(ar + ks * 32);
                    h8 a1 = *(const h8*)(ar + ks * 32 + 32);
                    acc = __builtin_amdgcn_mfma_f32_16x16x32_f16(a0, *(const h8*)(wb0 + ks * 32 + quad * 8), acc, 0, 0, 0);
                    acc2 = __builtin_amdgcn_mfma_f32_16x16x32_f16(a1, *(const h8*)(wb0 + ks * 32 + 32 + quad * 8), acc2, 0, 0, 0);
                }
            } else {
#pragma unroll
                for (int ks = 0; ks < 32; ks += 2) {
                    h8 a0 = *(const h8*)(ar + ks * 32);
                    h8 a1 = *(const h8*)(ar + ks * 32 + 32);
                    acc = __builtin_amdgcn_mfma_f32_16x16x32_f16(a0, wreg[ks], acc, 0, 0, 0);
                    acc2 = __builtin_amdgcn_mfma_f32_16x16x32_f16(a1, wreg[ks + 1], acc2, 0, 0, 0);
                }
            }
            const float bn = (t == 1) ? bias0 : biasE;
            const int bm = bh * 16 + quad * 4, cm = rg * 16 + lo;
#pragma unroll
            for (int r = 0; r < 4; ++r) s_g[bm + r][cm] = acc[r] + acc2[r] + bn;
            __syncthreads();
            {
                float gi = s_g[ub][ue * 4 + 0], gf = s_g[ub][ue * 4 + 1];
                float gg = s_g[ub][ue * 4 + 2], go = s_g[ub][ue * 4 + 3];
                float cn = sigm(gf) * s_c[ue][ub] + sigm(gi) * tanh_f(gg);
                s_c[ue][ub] = cn;
                s_hh[ue][ub] = (half_t)(sigm(go) * tanh_f(cn));
            }
            __syncthreads();
            if (tid < 64) {
                int b2 = tid >> 1, e8 = (tid & 1) * 8;
                union { half_t h[8]; u64 u[2]; } pk;
#pragma unroll
                for (int i = 0; i < 8; ++i) pk.h[i] = s_hh[e8 + i][b2];
                half_t* dst = hd + (size_t)sn * 32768 + (size_t)b2 * 1024 + j * 16 + e8;
                st_atom64(dst, pk.u[0]);
                st_atom64(dst + 4, pk.u[1]);
                // ack own data atomics, then fan out one flag per consumer
                asm volatile("s_waitcnt vmcnt(0)");
                st_atom32(mbD + ((size_t)tid * 64 + j), (unsigned)t);
                if (tid < 9)
                    st_atom32(mbD + ((size_t)(64 + tid) * 64 + j), (unsigned)t);
            }
            sp = sn; sn += HOP; if (sn >= RING_D) sn -= RING_D;
        }
    } else {
        // ---------------- lagging projection consumer block ----------------
        const int pj = j - 64;
        const bool meld = (pj < 8);
        const bool duty = (wv < 2);
        const int bh2 = wv & 1;
        const half_t* pw = meld ? (projwb + (size_t)(pj * 16 + lo) * 1024)
                                : (projg + (size_t)lo * 1024);
        const float biasP = meld ? projb[pj * 16 + lo] : gateb[0];

        h8 pwreg[32];
        if (duty) {
#pragma unroll
            for (int ks = 0; ks < 32; ++ks)
                pwreg[ks] = *(const h8*)(pw + ks * 32 + quad * 8);
        }
        if (tid < 32) s_len[tid] = mlens[tid];

        int spP = HOP;
        __syncthreads();

        for (int t = 1; t <= TMEL; ++t) {
            // wait for all producers of slot spP (contains h_t)
            if (tid < 64) {
                const unsigned want = (unsigned)t;
                const unsigned* fp = mbD + (size_t)(64 + pj) * 64 + tid;
                while (__hip_atomic_load(fp, __ATOMIC_RELAXED, __HIP_MEMORY_SCOPE_AGENT) < want)
                    __builtin_amdgcn_s_sleep(1);
            }
            __syncthreads();

            // cooperative load of h_t slot
            const half_t* src = hd + (size_t)spP * 32768;
            {
                h8 tp[8];
#pragma unroll
                for (int i = 0; i < 8; ++i)
                    tp[i] = *(const h8*)(src + (size_t)(tid + i * 512) * 8);
#pragma unroll
                for (int i = 0; i < 8; ++i) {
                    int c = tid + i * 512;
                    *(h8*)(s_hd + (size_t)(c >> 7) * 1032 + (c & 127) * 8) = tp[i];
                }
            }
            __syncthreads();

            if (duty) {
                const half_t* ar = s_hd + (size_t)(bh2 * 16 + lo) * 1032 + quad * 8;
                f4 accm = {0.f, 0.f, 0.f, 0.f}, accm2 = {0.f, 0.f, 0.f, 0.f};
#pragma unroll
                for (int ks = 0; ks < 32; ks += 2) {
                    h8 a0 = *(const h8*)(ar + ks * 32);
                    h8 a1 = *(const h8*)(ar + ks * 32 + 32);
                    accm = __builtin_amdgcn_mfma_f32_16x16x32_f16(a0, pwreg[ks], accm, 0, 0, 0);
                    accm2 = __builtin_amdgcn_mfma_f32_16x16x32_f16(a1, pwreg[ks + 1], accm2, 0, 0, 0);
                }
                accm[0] += accm2[0]; accm[1] += accm2[1];
                accm[2] += accm2[2]; accm[3] += accm2[3];
                const int pos = t - 1;
                if (meld) {
#pragma unroll
                    for (int r = 0; r < 4; ++r) {
                        int b = bh2 * 16 + quad * 4 + r;
                        float v = accm[r] + biasP;
                        if (pos > s_len[b]) v = 0.f;
                        __builtin_nontemporal_store(v,
                            &out[(size_t)b * (TMEL * MM) + (size_t)pos * MM + pj * 16 + lo]);
                    }
                } else if (lo == 0) {
#pragma unroll
                    for (int r = 0; r < 4; ++r) {
                        int b = bh2 * 16 + quad * 4 + r;
                        float v = accm[r] + biasP;
                        if (pos > s_len[b]) v = 1000.f;
                        __builtin_nontemporal_store(v, &out[GATE_OFF + (size_t)b * TMEL + pos]);
                    }
                }
            }
            __syncthreads();   // protect s_hd before next stage
            spP += HOP; if (spP >= RING_D) spP -= RING_D;
        }
    }
}

// ---------------------------------------------------------------------------

extern "C" void kernel_launch(void* const* d_in, const int* in_sizes, int n_in,
                              void* d_out, int out_size, void* d_ws, size_t ws_size,
                              hipStream_t stream) {
    const int* x = (const int*)d_in[0];
    const int* tlens = (const int*)d_in[1];
    const int* mlens = (const int*)d_in[3];
    const float* emb = (const float*)d_in[4];
    const float* c1w = (const float*)d_in[5];
    const float* c1b = (const float*)d_in[6];
    const float* bn1g = (const float*)d_in[7];
    const float* bn1b = (const float*)d_in[8];
    const float* c2w = (const float*)d_in[9];
    const float* c2b = (const float*)d_in[10];
    const float* bn2g = (const float*)d_in[11];
    const float* bn2b = (const float*)d_in[12];
    const float* wihf = (const float*)d_in[13];
    const float* whhf = (const float*)d_in[14];
    const float* bihf = (const float*)d_in[15];
    const float* bhhf = (const float*)d_in[16];
    const float* wihb = (const float*)d_in[17];
    const float* whhb = (const float*)d_in[18];
    const float* bihb = (const float*)d_in[19];
    const float* bhhb = (const float*)d_in[20];
    const float* dwih = (const float*)d_in[21];
    const float* dwhh = (const float*)d_in[22];
    const float* dbih = (const float*)d_in[23];
    const float* dbhh = (const float*)d_in[24];
    const float* projw = (const float*)d_in[25];
    const float* projb = (const float*)d_in[26];
    const float* gatew = (const float*)d_in[27];
    const float* gateb = (const float*)d_in[28];
    float* out = (float*)d_out;
    char* ws = (char*)d_ws;

    unsigned* mbE = (unsigned*)(ws + WS_MBE);
    unsigned* mbD = (unsigned*)(ws + WS_MBD);
    half_t* henc = (half_t*)(ws + WS_HENC);
    half_t* hd = (half_t*)(ws + WS_HD);
    half_t* bufX = (half_t*)(ws + WS_BUFX);
    half_t* bufY = (half_t*)(ws + WS_BUFY);
    float* convf = (float*)(ws + WS_CONVF);
    half_t* weff = (half_t*)(ws + WS_WEFF);
    half_t* w0 = (half_t*)(ws + WS_W0);
    half_t* wp1 = (half_t*)(ws + WS_WP1);
    half_t* wp2 = (half_t*)(ws + WS_WP2);
    float* meanb = (float*)(ws + WS_MEAN);
    float* rstdb = (float*)(ws + WS_RSTD);
    half_t* wihp = (half_t*)(ws + WS_WIHP);
    half_t* whhp = (half_t*)(ws + WS_WHHP);
    float* bsum = (float*)(ws + WS_BSUM);
    float* beff = (float*)(ws + WS_BEFF);
    float* b0 = (float*)(ws + WS_B0);
    half_t* projwb = (half_t*)(ws + WS_PROJW);
    half_t* projg = (half_t*)(ws + WS_PROJG);
    float* cel = (float*)(ws + WS_CEL);

    // zero mailboxes + encoder ring slot 0 (re-done every launch/replay)
    hipMemsetAsync(d_ws, 0, (size_t)WS_ZERO_BYTES, stream);

    // front-end
    k_embed<<<NROWS, 256, 0, stream>>>(x, emb, bufX);
    k_packconvw<<<(3 * EE * EE + 255) / 256, 256, 0, stream>>>(c1w, wp1);
    k_conv<<<dim3(128, 32), 256, 0, stream>>>(bufX, wp1, c1b, convf);
    k_bnstats<<<EE, 256, 0, stream>>>(convf, meanb, rstdb);
    k_bnapply<<<(NROWS * EE) / 256, 256, 0, stream>>>(convf, meanb, rstdb, bn1g, bn1b, bufY);
    k_packconvw<<<(3 * EE * EE + 255) / 256, 256, 0, stream>>>(c2w, wp2);
    k_conv<<<dim3(128, 32), 256, 0, stream>>>(bufY, wp2, c2b, convf);
    k_bnstats<<<EE, 256, 0, stream>>>(convf, meanb, rstdb);
    k_bnapply<<<(NROWS * EE) / 256, 256, 0, stream>>>(convf, meanb, rstdb, bn2g, bn2b, bufX);

    // encoder weight prep
    const int encTot = 2048 * 512;
    k_packrec<<<(encTot + 255) / 256, 256, 0, stream>>>(wihf, wihp, HH, 9, encTot);
    k_packrec<<<(encTot + 255) / 256, 256, 0, stream>>>(wihb, wihp + encTot, HH, 9, encTot);
    k_packrec<<<(encTot + 255) / 256, 256, 0, stream>>>(whhf, whhp, HH, 9, encTot);
    k_packrec<<<(encTot + 255) / 256, 256, 0, stream>>>(whhb, whhp + encTot, HH, 9, encTot);
    k_bsumenc<<<16, 256, 0, stream>>>(bihf, bhhf, bihb, bhhb, bsum);

    // persistent bidirectional encoder (writes hd ring slot 0 + cel)
    k_enc<<<64, 512, 0, stream>>>(bufX, wihp, whhp, bsum, tlens, henc, hd, cel, mbE);

    // decoder weight prep (into retired convf region)
    k_weff<<<dim3(4096, 4), 256, 0, stream>>>(dwhh, dwih, projw, weff, w0);
    k_bdec<<<16, 256, 0, stream>>>(dbih, dbhh, dwih, projb, beff, b0);
    k_cast<<<(MM * DD + 255) / 256, 256, 0, stream>>>(projw, projwb, MM * DD);
    k_projg<<<(16 * DD + 255) / 256, 256, 0, stream>>>(gatew, projg);

    // persistent decoder (64 core + 9 projection blocks)
    k_dec<<<73, 512, 0, stream>>>(weff, w0, beff, b0, projwb, projg, projb, gateb,
                                  mlens, cel, hd, out, mbD);

    // mask output
    k_mask<<<(B_ * TMEL + 255) / 256, 256, 0, stream>>>(mlens, out);

    (void)in_sizes; (void)n_in; (void)out_size; (void)ws_size;
}